// Round 6
// baseline (535.012 us; speedup 1.0000x reference)
//
#include <hip/hip_runtime.h>
#include <hip/hip_bf16.h>

// Problem: B=2, T=2048, C=2048, NQ=16, NKV=4, H=128, EPS=1e-6
// DTYPE GROUND TRUTH (established rounds 1-6): ALL inputs f32, output f32.
// Internals: bf16 (weights pre-converted; x converted during LDS staging).
#define B_   2
#define T_   2048
#define C_   2048
#define NQ_  16
#define NKV_ 4
#define H_   128

using bf16x8 = __attribute__((ext_vector_type(8))) short;
using f32x4  = __attribute__((ext_vector_type(4))) float;

__device__ __forceinline__ unsigned short f2bf(float f) {
    __hip_bfloat16 h = __float2bfloat16(f);  // RNE
    union { __hip_bfloat16 h; unsigned short s; } c;
    c.h = h;
    return c.s;
}
__device__ __forceinline__ float bf2f(unsigned short s) {
    return __uint_as_float(((unsigned)s) << 16);
}
__device__ __forceinline__ bf16x8 pack8(float4 f0, float4 f1) {
    bf16x8 r;
    r[0] = (short)f2bf(f0.x); r[1] = (short)f2bf(f0.y);
    r[2] = (short)f2bf(f0.z); r[3] = (short)f2bf(f0.w);
    r[4] = (short)f2bf(f1.x); r[5] = (short)f2bf(f1.y);
    r[6] = (short)f2bf(f1.z); r[7] = (short)f2bf(f1.w);
    return r;
}

#define MFMA16(a, b, c) __builtin_amdgcn_mfma_f32_16x16x32_bf16(a, b, c, 0, 0, 0)

// ---------------------------------------------------------------------------
// 64x64-tile transpose + f32->bf16 convert: dst[c][r] = bf16(src[r][c]).
// ---------------------------------------------------------------------------
__global__ void transpose_cvt(const float* __restrict__ src,
                              unsigned short* __restrict__ dst,
                              int R, int Cc) {
    const int tc = Cc >> 6;
    const int r0 = (blockIdx.x / tc) * 64;
    const int c0 = (blockIdx.x % tc) * 64;
    __shared__ unsigned short Tl[64 * 65];
    const int tid = threadIdx.x;
#pragma unroll
    for (int it = 0; it < 16; ++it) {
        const int idx = it * 256 + tid;
        const int r = idx >> 6, c = idx & 63;
        Tl[c * 65 + r] = f2bf(src[(size_t)(r0 + r) * Cc + c0 + c]);
    }
    __syncthreads();
#pragma unroll
    for (int it = 0; it < 16; ++it) {
        const int idx = it * 256 + tid;
        const int c = idx >> 6, r = idx & 63;
        dst[(size_t)(c0 + c) * R + r0 + r] = Tl[c * 65 + r];
    }
}

// ---------------------------------------------------------------------------
// 128x128-tile GEMM: C = A @ Bt^T.
// NEW: for the fused-QKV V-columns (nb >= 2560) the epilogue writes the
// output TRANSPOSED per (b,kvh): Vt_g[(b*4+kvh)][d][token] via an LDS
// transpose — V needs no norm/rope, so this is its final layout and the
// flash kernel can load V fragments directly from global (barrier-free PV).
// ---------------------------------------------------------------------------
#define LDP 40

template <bool A_BF, bool OUT_F32>
__global__ __launch_bounds__(256, 2) void gemm_bt(
    const void* __restrict__ Av,
    const unsigned short* __restrict__ Bt,
    void* __restrict__ Cqv,
    unsigned short* __restrict__ Ck,
    unsigned short* __restrict__ Cv,
    int M, int N, int K, int fused) {
    const int ntn = N >> 7;
    const int tm  = blockIdx.x / ntn;
    const int tn  = blockIdx.x % ntn;

    const int tid  = threadIdx.x;
    const int wv   = tid >> 6;
    const int lane = tid & 63;
    const int col  = lane & 15;
    const int quad = lane >> 4;
    const int wm   = (wv & 1) * 64;
    const int wn   = (wv >> 1) * 64;

    // 17408 u16 = 34816 B. Main loop uses [0, 10240); the V-transpose
    // epilogue aliases the whole array as Tl[128][136].
    __shared__ unsigned short gsm[17408];
    unsigned short* Al = gsm;
    unsigned short* Bl = gsm + 128 * LDP;

    f32x4 acc[4][4];
#pragma unroll
    for (int mt = 0; mt < 4; ++mt)
#pragma unroll
        for (int nt = 0; nt < 4; ++nt) acc[mt][nt] = (f32x4){0.f, 0.f, 0.f, 0.f};

    const int i1 = tid, i2 = tid + 256;
    const size_t aoff1 = (size_t)(tm * 128 + (i1 >> 2)) * K + (i1 & 3) * 8;
    const size_t aoff2 = (size_t)(tm * 128 + (i2 >> 2)) * K + (i2 & 3) * 8;
    const size_t boff1 = (size_t)(tn * 128 + (i1 >> 2)) * K + (i1 & 3) * 8;
    const size_t boff2 = (size_t)(tn * 128 + (i2 >> 2)) * K + (i2 & 3) * 8;
    unsigned short* Aw1 = Al + (i1 >> 2) * LDP + (i1 & 3) * 8;
    unsigned short* Aw2 = Al + (i2 >> 2) * LDP + (i2 & 3) * 8;
    unsigned short* Bw1 = Bl + (i1 >> 2) * LDP + (i1 & 3) * 8;
    unsigned short* Bw2 = Bl + (i2 >> 2) * LDP + (i2 & 3) * 8;

    const unsigned short* Ab16 = (const unsigned short*)Av;
    const float*          Af   = (const float*)Av;

    uint4  a1u, a2u, b1u, b2u;
    float4 a1lo, a1hi, a2lo, a2hi;

    auto loadAB = [&](int kk) {
        if constexpr (A_BF) {
            a1u = *(const uint4*)(Ab16 + aoff1 + kk);
            a2u = *(const uint4*)(Ab16 + aoff2 + kk);
        } else {
            a1lo = *(const float4*)(Af + aoff1 + kk);
            a1hi = *(const float4*)(Af + aoff1 + kk + 4);
            a2lo = *(const float4*)(Af + aoff2 + kk);
            a2hi = *(const float4*)(Af + aoff2 + kk + 4);
        }
        b1u = *(const uint4*)(Bt + boff1 + kk);
        b2u = *(const uint4*)(Bt + boff2 + kk);
    };

    loadAB(0);

    for (int k0 = 0; k0 < K; k0 += 32) {
        __syncthreads();
        if constexpr (A_BF) {
            *(uint4*)Aw1 = a1u;
            *(uint4*)Aw2 = a2u;
        } else {
            *(bf16x8*)Aw1 = pack8(a1lo, a1hi);
            *(bf16x8*)Aw2 = pack8(a2lo, a2hi);
        }
        *(uint4*)Bw1 = b1u;
        *(uint4*)Bw2 = b2u;
        __syncthreads();

        const int kn = (k0 + 32 < K) ? k0 + 32 : k0;
        loadAB(kn);

        bf16x8 af[4], bfv[4];
#pragma unroll
        for (int t = 0; t < 4; ++t) {
            af[t]  = *(const bf16x8*)(Al + (wm + t * 16 + col) * LDP + quad * 8);
            bfv[t] = *(const bf16x8*)(Bl + (wn + t * 16 + col) * LDP + quad * 8);
        }
#pragma unroll
        for (int mt = 0; mt < 4; ++mt)
#pragma unroll
            for (int nt = 0; nt < 4; ++nt)
                acc[mt][nt] = MFMA16(af[mt], bfv[nt], acc[mt][nt]);
    }

    const int nb = tn * 128;
    if constexpr (OUT_F32) {
        float* Co = (float*)Cqv;
#pragma unroll
        for (int mt = 0; mt < 4; ++mt)
#pragma unroll
            for (int nt = 0; nt < 4; ++nt)
#pragma unroll
                for (int r = 0; r < 4; ++r) {
                    const int row = tm * 128 + wm + mt * 16 + quad * 4 + r;
                    const int cc  = nb + wn + nt * 16 + col;
                    Co[(size_t)row * N + cc] = acc[mt][nt][r];
                }
    } else {
        if (fused && nb >= 2560) {
            // ---- V tile: LDS-transpose then write Vt_g[(b*4+kvh)][d][t] ----
            __syncthreads();  // main-loop LDS reads done before aliasing
#pragma unroll
            for (int mt = 0; mt < 4; ++mt)
#pragma unroll
                for (int nt = 0; nt < 4; ++nt)
#pragma unroll
                    for (int r = 0; r < 4; ++r) {
                        const int lr = wm + mt * 16 + quad * 4 + r;  // token
                        const int lc = wn + nt * 16 + col;           // dim
                        gsm[lc * 136 + lr] = f2bf(acc[mt][nt][r]);
                    }
            __syncthreads();
            const int kvh = (nb - 2560) >> 7;
            const int bb  = tm >> 4;
            const int t0  = (tm & 15) * 128;
            unsigned short* dst = Cv + (((size_t)(bb * 4 + kvh)) << 18) + t0;
#pragma unroll
            for (int it = 0; it < 8; ++it) {
                const int d = (tid >> 4) + it * 16;
                const int t = (tid & 15) * 8;
                *(uint4*)(dst + (size_t)d * 2048 + t) = *(const uint4*)(gsm + d * 136 + t);
            }
        } else {
            unsigned short* Cb;
            int ldc, nc0;
            if (!fused)         { Cb = (unsigned short*)Cqv; ldc = N;    nc0 = nb;        }
            else if (nb < 2048) { Cb = (unsigned short*)Cqv; ldc = 2048; nc0 = nb;        }
            else                { Cb = Ck;                   ldc = 512;  nc0 = nb - 2048; }
#pragma unroll
            for (int mt = 0; mt < 4; ++mt)
#pragma unroll
                for (int nt = 0; nt < 4; ++nt)
#pragma unroll
                    for (int r = 0; r < 4; ++r) {
                        const int row = tm * 128 + wm + mt * 16 + quad * 4 + r;
                        const int cc  = nc0 + wn + nt * 16 + col;
                        Cb[(size_t)row * ldc + cc] = f2bf(acc[mt][nt][r]);
                    }
        }
    }
}

// ---------------------------------------------------------------------------
// Fused per-head RMSNorm + RoPE. oscale folds log2(e)/sqrt(H) into Q so the
// flash kernel's scores come out pre-scaled for the exp2-domain softmax.
// ---------------------------------------------------------------------------
__global__ void norm_rope(unsigned short* __restrict__ buf,
                          const float* __restrict__ w,
                          const float* __restrict__ cosb,
                          const float* __restrict__ sinb,
                          int nheads, float oscale) {
    const int idx = blockIdx.x;
    const int h   = idx % nheads;
    const int bt  = idx / nheads;
    const int t   = bt % T_;
    unsigned short* row = buf + ((size_t)bt * nheads + h) * H_;
    const int l = threadIdx.x;  // 0..63

    const float x0 = bf2f(row[l]);
    const float x1 = bf2f(row[l + 64]);
    float ss = x0 * x0 + x1 * x1;
#pragma unroll
    for (int off = 32; off; off >>= 1) ss += __shfl_xor(ss, off);
    const float r = rsqrtf(ss * (1.0f / 128.0f) + 1e-6f) * oscale;

    const float n0 = x0 * r * w[l];
    const float n1 = x1 * r * w[l + 64];
    const float c0 = cosb[t * H_ + l];
    const float c1 = cosb[t * H_ + l + 64];
    const float s0 = sinb[t * H_ + l];
    const float s1 = sinb[t * H_ + l + 64];

    row[l]      = f2bf(n0 * c0 - n1 * s0);
    row[l + 64] = f2bf(n1 * c1 + n0 * s1);
}

// ---------------------------------------------------------------------------
// MFMA flash attention v7: BARRIER-FREE main loop.
//   Theory (round-5 PMC): per-iteration time 15.1k cyc vs ~3k of pipe work —
//   the block-wide barriers lockstep all 8 waves into the same phase, so
//   every serial dependency stalls every wave simultaneously. Fix: remove
//   all staging barriers by making each wave self-sufficient:
//     * K direct-to-reg (v6, proven).
//     * V direct-to-reg from the pre-transposed Vt_g written by the QKV GEMM
//       (contiguous 16B fragments, same layout LDS staging used to produce).
//     * P through a PRIVATE per-wave LDS slice (same-wave ds ordering).
//     * kf/vf prefetched one chunk ahead (kf refilled after softmax, vf after
//       PV) -> global latency hides under compute, no waitcnt coupling.
//   Pair-split schedule + in-LDS merge retained (barriers only at merge).
// LDS: loop: P 8x2304 u16 = 36864 B + alf 1024 B; merge (aliased): Of 65536 B
//   + mlA/mlB 2048 B. Total 67584 B, 1 block/CU (grid == 256).
// ---------------------------------------------------------------------------
__global__ __launch_bounds__(512, 2) void flash_attn(
    const unsigned short* __restrict__ qbuf,
    const unsigned short* __restrict__ kbuf,
    const unsigned short* __restrict__ vtg,
    unsigned short* __restrict__ ctx) {
    const int blk = blockIdx.x;            // 256 blocks
    const int p   = blk & 7;               // pair: tiles p and 15-p
    const int h   = (blk >> 3) & 15;
    const int b   = blk >> 7;
    const int kvh = h >> 2;
    const int qtB = 15 - p;

    const int tid  = threadIdx.x;
    const int wave = tid >> 6;             // 0..7
    const int g    = wave >> 2;            // 0 = group A, 1 = group B
    const int gw   = wave & 3;             // wave-in-group
    const int lane = tid & 63;
    const int col  = lane & 15;
    const int quad = lane >> 4;

    int w0 = (g ? qtB : p) * 128 + gw * 32;   // active 32 q-rows
    const int ph1 = 2 * p + 2;                // group A's own-tile chunk count

    __shared__ __align__(16) unsigned char smem[67584];
    unsigned short* Pw   = (unsigned short*)smem + wave * 2304;  // [32][72]
    float*          alfw = (float*)(smem + 36864) + wave * 32;   // [32]

    // Q fragments for active rows, pre-scaled by log2(e)/sqrt(H)
    bf16x8 qf[2][4];
    auto loadQ = [&]() {
#pragma unroll
        for (int nt = 0; nt < 2; ++nt)
#pragma unroll
            for (int ks = 0; ks < 4; ++ks) {
                const size_t off =
                    ((size_t)(b * T_ + w0 + nt * 16 + col) * NQ_ + h) * H_ + ks * 32 + quad * 8;
                qf[nt][ks] = *(const bf16x8*)(qbuf + off);
            }
    };
    loadQ();

    f32x4 O[2][8];
#pragma unroll
    for (int pt = 0; pt < 2; ++pt)
#pragma unroll
        for (int dt = 0; dt < 8; ++dt) O[pt][dt] = (f32x4){0.f, 0.f, 0.f, 0.f};
    float m_run[2] = {-3.0e38f, -3.0e38f};
    float l_run[2] = {0.f, 0.f};

    // ---- K direct-to-register ----
    bf16x8 kf[4][4];  // [mt][ks]
    const unsigned short* kb = kbuf + ((size_t)(b * T_) * NKV_ + kvh) * H_;
    const int koff = col * (NKV_ * H_) + quad * 8;
    auto loadK = [&](int j0) {
#pragma unroll
        for (int mt = 0; mt < 4; ++mt) {
            const unsigned short* kr = kb + (size_t)((j0 + mt * 16) * (NKV_ * H_) + koff);
#pragma unroll
            for (int ks = 0; ks < 4; ++ks)
                kf[mt][ks] = *(const bf16x8*)(kr + ks * 32);
        }
    };

    // ---- V direct-to-register from transposed Vt_g ----
    bf16x8 vf[16];  // [dt*2+ks]
    const unsigned short* vb =
        vtg + (((size_t)(b * NKV_ + kvh)) << 18) + col * 2048 + quad * 8;
    auto loadV = [&](int j0) {
#pragma unroll
        for (int dt = 0; dt < 8; ++dt)
#pragma unroll
            for (int ks = 0; ks < 2; ++ks)
                vf[dt * 2 + ks] = *(const bf16x8*)(vb + (size_t)dt * 32768 + j0 + ks * 32);
    };

    // tile-A epilogue (group A only, per-wave, no barriers)
    auto storeOut = [&]() {
        if (quad == 0) {
            alfw[col]      = 1.0f / l_run[0];
            alfw[col + 16] = 1.0f / l_run[1];
        }
        const f32x4 i0 = *(const f32x4*)&alfw[quad * 4];
        const f32x4 i1 = *(const f32x4*)&alfw[quad * 4 + 16];
#pragma unroll
        for (int pt = 0; pt < 2; ++pt)
#pragma unroll
            for (int r = 0; r < 4; ++r) {
                const float inv = pt ? i1[r] : i0[r];
                const int ig = w0 + pt * 16 + quad * 4 + r;
                unsigned short* op = ctx + ((size_t)(b * T_ + ig) * NQ_ + h) * H_;
#pragma unroll
                for (int dt = 0; dt < 8; ++dt)
                    op[dt * 16 + col] = f2bf(O[pt][dt][r] * inv);
            }
    };

    // group chunk schedule: B: 0..16; A: 0..ph1-1 (own), then 17..(31-2p)
    auto chunk_of = [&](int i) { return g ? i : (i < ph1 ? i : i + 15 - 2 * p); };

    loadK(0);
    loadV(0);

    for (int i = 0; i < 17; ++i) {
        const int j0 = chunk_of(i) * 64;

        // group A: transition from own tile to B-tile partial
        if (g == 0 && i == ph1) {
            storeOut();  // tile p is complete -> ctx
#pragma unroll
            for (int pt = 0; pt < 2; ++pt)
#pragma unroll
                for (int dt = 0; dt < 8; ++dt) O[pt][dt] = (f32x4){0.f, 0.f, 0.f, 0.f};
            m_run[0] = m_run[1] = -3.0e38f;
            l_run[0] = l_run[1] = 0.f;
            w0 = qtB * 128 + gw * 32;
            loadQ();
        }

        const bool act = (j0 <= w0 + 31);  // this wave has unmasked keys here

        // ---- swapped QK^T: St[key-tile][q-tile], 32 MFMAs, operands in regs ----
        f32x4 St[4][2];
        if (act) {
#pragma unroll
            for (int mt = 0; mt < 4; ++mt)
#pragma unroll
                for (int nt = 0; nt < 2; ++nt) St[mt][nt] = (f32x4){0.f, 0.f, 0.f, 0.f};
#pragma unroll
            for (int ks = 0; ks < 4; ++ks)
#pragma unroll
                for (int mt = 0; mt < 4; ++mt) {
                    St[mt][0] = MFMA16(kf[mt][ks], qf[0][ks], St[mt][0]);
                    St[mt][1] = MFMA16(kf[mt][ks], qf[1][ks], St[mt][1]);
                }

            // ---- mask (acc row = key, col = query) ----
            const bool needmask = (j0 + 63 > w0);
            if (needmask) {
                const int ig0 = w0 + col;
#pragma unroll
                for (int mt = 0; mt < 4; ++mt)
#pragma unroll
                    for (int r = 0; r < 4; ++r) {
                        const int key = j0 + mt * 16 + quad * 4 + r;
                        if (key > ig0)      St[mt][0][r] = -3.0e38f;
                        if (key > ig0 + 16) St[mt][1][r] = -3.0e38f;
                    }
            }

            // ---- in-lane row max ----
            float rm[2];
#pragma unroll
            for (int nt = 0; nt < 2; ++nt) {
                float m0 = fmaxf(fmaxf(St[0][nt][0], St[0][nt][1]),
                                 fmaxf(St[0][nt][2], St[0][nt][3]));
#pragma unroll
                for (int mt = 1; mt < 4; ++mt)
                    m0 = fmaxf(m0, fmaxf(fmaxf(St[mt][nt][0], St[mt][nt][1]),
                                         fmaxf(St[mt][nt][2], St[mt][nt][3])));
                m0 = fmaxf(m0, __shfl_xor(m0, 16));
                m0 = fmaxf(m0, __shfl_xor(m0, 32));
                rm[nt] = m0;
            }

            // ---- defer-max (THR=8, exp2 domain) ----
            const int defer = __all((rm[0] <= m_run[0] + 8.0f) && (rm[1] <= m_run[1] + 8.0f));
            if (!defer) {
                const float mn0 = fmaxf(m_run[0], rm[0]);
                const float mn1 = fmaxf(m_run[1], rm[1]);
                const float al0 = exp2f(m_run[0] - mn0);
                const float al1 = exp2f(m_run[1] - mn1);
                m_run[0] = mn0; m_run[1] = mn1;
                l_run[0] *= al0; l_run[1] *= al1;
                if (quad == 0) { alfw[col] = al0; alfw[col + 16] = al1; }
            }

            // ---- P = exp2(S - m), in-lane sum, b64 packed writes ----
            float ls0 = 0.f, ls1 = 0.f;
#pragma unroll
            for (int mt = 0; mt < 4; ++mt) {
                const float p0 = exp2f(St[mt][0][0] - m_run[0]);
                const float p1 = exp2f(St[mt][0][1] - m_run[0]);
                const float p2 = exp2f(St[mt][0][2] - m_run[0]);
                const float p3 = exp2f(St[mt][0][3] - m_run[0]);
                ls0 += (p0 + p1) + (p2 + p3);
                *(uint2*)(Pw + col * 72 + mt * 16 + quad * 4) =
                    make_uint2((unsigned)f2bf(p0) | ((unsigned)f2bf(p1) << 16),
                               (unsigned)f2bf(p2) | ((unsigned)f2bf(p3) << 16));
                const float q0 = exp2f(St[mt][1][0] - m_run[1]);
                const float q1 = exp2f(St[mt][1][1] - m_run[1]);
                const float q2 = exp2f(St[mt][1][2] - m_run[1]);
                const float q3 = exp2f(St[mt][1][3] - m_run[1]);
                ls1 += (q0 + q1) + (q2 + q3);
                *(uint2*)(Pw + (col + 16) * 72 + mt * 16 + quad * 4) =
                    make_uint2((unsigned)f2bf(q0) | ((unsigned)f2bf(q1) << 16),
                               (unsigned)f2bf(q2) | ((unsigned)f2bf(q3) << 16));
            }
            ls0 += __shfl_xor(ls0, 16); ls0 += __shfl_xor(ls0, 32);
            ls1 += __shfl_xor(ls1, 16); ls1 += __shfl_xor(ls1, 32);
            l_run[0] += ls0; l_run[1] += ls1;

            // ---- O rescale (only when not deferred) ----
            if (!defer) {
                const f32x4 a0 = *(const f32x4*)&alfw[quad * 4];
                const f32x4 a1 = *(const f32x4*)&alfw[quad * 4 + 16];
#pragma unroll
                for (int dt = 0; dt < 8; ++dt)
#pragma unroll
                    for (int r = 0; r < 4; ++r) { O[0][dt][r] *= a0[r]; O[1][dt][r] *= a1[r]; }
            }
        }

        // refill kf for next chunk (kf dead after QK; PV below hides latency)
        if (i + 1 < 17) loadK(chunk_of(i + 1) * 64);

        if (act) {
            // ---- PV: O += P(32x64) @ V(64x128), 32 MFMAs, V in regs ----
#pragma unroll
            for (int ks = 0; ks < 2; ++ks) {
                const bf16x8 pa0 = *(const bf16x8*)(Pw + col * 72 + ks * 32 + quad * 8);
                const bf16x8 pa1 = *(const bf16x8*)(Pw + (col + 16) * 72 + ks * 32 + quad * 8);
#pragma unroll
                for (int dt = 0; dt < 8; ++dt) {
                    O[0][dt] = MFMA16(pa0, vf[dt * 2 + ks], O[0][dt]);
                    O[1][dt] = MFMA16(pa1, vf[dt * 2 + ks], O[1][dt]);
                }
            }
        }

        // refill vf for next chunk (vf dead after PV; next QK+softmax hides it)
        if (i + 1 < 17) loadV(chunk_of(i + 1) * 64);
    }

    // ---- merge: combine B-tile partials (A: keys >= 1088, B: keys < 1088) ----
    __syncthreads();  // all waves done with P/alf; alias Of over them
    float* mlA = (float*)(smem + 65536);  // [4][32][2]
    float* mlB = (float*)(smem + 66560);  // [4][32][2]
    if (g == 0) {
        float* Of = (float*)smem + gw * 4096;  // [32][128] raw O
        float* ml = mlA + gw * 64;
        if (quad == 0) {
            ml[2 * col]            = m_run[0]; ml[2 * col + 1]        = l_run[0];
            ml[2 * (col + 16)]     = m_run[1]; ml[2 * (col + 16) + 1] = l_run[1];
        }
#pragma unroll
        for (int pt = 0; pt < 2; ++pt)
#pragma unroll
            for (int dt = 0; dt < 8; ++dt)
#pragma unroll
                for (int r = 0; r < 4; ++r)
                    Of[(pt * 16 + quad * 4 + r) * 128 + dt * 16 + col] = O[pt][dt][r];
    }
    __syncthreads();
    if (g == 1) {
        float* Of = (float*)smem + gw * 4096;
        float* mA = mlA + gw * 64;
        float* mB = mlB + gw * 64;
        if (quad == 0) {
            mB[2 * col]            = m_run[0]; mB[2 * col + 1]        = l_run[0];
            mB[2 * (col + 16)]     = m_run[1]; mB[2 * (col + 16) + 1] = l_run[1];
        }
#pragma unroll
        for (int pt = 0; pt < 2; ++pt)
#pragma unroll
            for (int r = 0; r < 4; ++r) {
                const int row = pt * 16 + quad * 4 + r;
                const float mBv = mB[2 * row], lBv = mB[2 * row + 1];
                const float mAv = mA[2 * row], lAv = mA[2 * row + 1];
                const float m  = fmaxf(mAv, mBv);
                const float aB = exp2f(mBv - m);
                const float aA = exp2f(mAv - m);
                const float inv = 1.0f / (lBv * aB + lAv * aA);
                const int ig = w0 + row;
                unsigned short* op = ctx + ((size_t)(b * T_ + ig) * NQ_ + h) * H_;
#pragma unroll
                for (int dt = 0; dt < 8; ++dt)
                    op[dt * 16 + col] =
                        f2bf((O[pt][dt][r] * aB + Of[row * 128 + dt * 16 + col] * aA) * inv);
            }
    }
}

// ---------------------------------------------------------------------------
extern "C" void kernel_launch(void* const* d_in, const int* in_sizes, int n_in,
                              void* d_out, int out_size, void* d_ws, size_t ws_size,
                              hipStream_t stream) {
    const float* x    = (const float*)d_in[0];
    const float* Wq   = (const float*)d_in[1];
    const float* Wk   = (const float*)d_in[2];
    const float* Wv   = (const float*)d_in[3];
    const float* Wo   = (const float*)d_in[4];
    const float* qnw  = (const float*)d_in[5];
    const float* knw  = (const float*)d_in[6];
    const float* cosb = (const float*)d_in[7];
    const float* sinb = (const float*)d_in[8];
    // d_in[9] = attn_mask: exact causal tril(0/-1e9) -> implemented directly

    const int M = B_ * T_;  // 4096
    // ws layout (u16 offsets), 42 MB footprint (unchanged):
    //   WqT/WkT/WvT [0,6291456) dead after QKV; ctx [0,8388608) aliases them
    //   q [8388608,16777216) (WoT aliases after attn); k; vtg (V transposed)
    unsigned short* ws  = (unsigned short*)d_ws;
    unsigned short* WqT = ws;
    unsigned short* WkT = WqT + (size_t)2048 * 2048;
    unsigned short* WvT = WkT + (size_t)512 * 2048;
    unsigned short* ctx = ws;
    unsigned short* q   = ws + (size_t)8388608;
    unsigned short* k   = ws + (size_t)16777216;
    unsigned short* vtg = ws + (size_t)18874368;  // [B*NKV][128][2048]
    unsigned short* WoT = q;

    transpose_cvt<<<(2048 / 64) * (2048 / 64), 256, 0, stream>>>(Wq, WqT, 2048, 2048);
    transpose_cvt<<<(2048 / 64) * (512 / 64),  256, 0, stream>>>(Wk, WkT, 2048, 512);
    transpose_cvt<<<(2048 / 64) * (512 / 64),  256, 0, stream>>>(Wv, WvT, 2048, 512);

    gemm_bt<false, false><<<(M / 128) * (3072 / 128), 256, 0, stream>>>(
        (const void*)x, WqT, (void*)q, k, vtg, M, 3072, C_, 1);

    // Q pre-scaled by log2(e)/sqrt(128) for the exp2-domain softmax
    norm_rope<<<M * NQ_, 64, 0, stream>>>(q, qnw, cosb, sinb, NQ_, 0.12751743f);
    norm_rope<<<M * NKV_, 64, 0, stream>>>(k, knw, cosb, sinb, NKV_, 1.0f);

    flash_attn<<<256, 512, 0, stream>>>(q, k, vtg, ctx);

    transpose_cvt<<<(2048 / 64) * (2048 / 64), 256, 0, stream>>>(Wo, WoT, 2048, 2048);
    gemm_bt<true, true><<<(M / 128) * (C_ / 128), 256, 0, stream>>>(
        (const void*)ctx, WoT, d_out, nullptr, nullptr, M, C_, NQ_ * H_, 0);
}

// Round 7
// 425.395 us; speedup vs baseline: 1.2577x; 1.2577x over previous
//
#include <hip/hip_runtime.h>
#include <hip/hip_bf16.h>

// Problem: B=2, T=2048, C=2048, NQ=16, NKV=4, H=128, EPS=1e-6
// DTYPE GROUND TRUTH (established rounds 1-6): ALL inputs f32, output f32.
// Internals: bf16 (weights pre-converted; x converted during LDS staging).
#define B_   2
#define T_   2048
#define C_   2048
#define NQ_  16
#define NKV_ 4
#define H_   128

using bf16x8 = __attribute__((ext_vector_type(8))) short;
using f32x4  = __attribute__((ext_vector_type(4))) float;

__device__ __forceinline__ unsigned short f2bf(float f) {
    __hip_bfloat16 h = __float2bfloat16(f);  // RNE
    union { __hip_bfloat16 h; unsigned short s; } c;
    c.h = h;
    return c.s;
}
__device__ __forceinline__ float bf2f(unsigned short s) {
    return __uint_as_float(((unsigned)s) << 16);
}
__device__ __forceinline__ bf16x8 pack8(float4 f0, float4 f1) {
    bf16x8 r;
    r[0] = (short)f2bf(f0.x); r[1] = (short)f2bf(f0.y);
    r[2] = (short)f2bf(f0.z); r[3] = (short)f2bf(f0.w);
    r[4] = (short)f2bf(f1.x); r[5] = (short)f2bf(f1.y);
    r[6] = (short)f2bf(f1.z); r[7] = (short)f2bf(f1.w);
    return r;
}

#define MFMA16(a, b, c) __builtin_amdgcn_mfma_f32_16x16x32_bf16(a, b, c, 0, 0, 0)

// ---------------------------------------------------------------------------
// 64x64-tile transpose + f32->bf16 convert: dst[c][r] = bf16(src[r][c]).
// ---------------------------------------------------------------------------
__global__ void transpose_cvt(const float* __restrict__ src,
                              unsigned short* __restrict__ dst,
                              int R, int Cc) {
    const int tc = Cc >> 6;
    const int r0 = (blockIdx.x / tc) * 64;
    const int c0 = (blockIdx.x % tc) * 64;
    __shared__ unsigned short Tl[64 * 65];
    const int tid = threadIdx.x;
#pragma unroll
    for (int it = 0; it < 16; ++it) {
        const int idx = it * 256 + tid;
        const int r = idx >> 6, c = idx & 63;
        Tl[c * 65 + r] = f2bf(src[(size_t)(r0 + r) * Cc + c0 + c]);
    }
    __syncthreads();
#pragma unroll
    for (int it = 0; it < 16; ++it) {
        const int idx = it * 256 + tid;
        const int c = idx >> 6, r = idx & 63;
        dst[(size_t)(c0 + c) * R + r0 + r] = Tl[c * 65 + r];
    }
}

// ---------------------------------------------------------------------------
// 128x128-tile GEMM (v6-verified): C = A @ Bt^T.
// ---------------------------------------------------------------------------
#define LDP 40

template <bool A_BF, bool OUT_F32>
__global__ __launch_bounds__(256, 2) void gemm_bt(
    const void* __restrict__ Av,
    const unsigned short* __restrict__ Bt,
    void* __restrict__ Cqv,
    unsigned short* __restrict__ Ck,
    unsigned short* __restrict__ Cv,
    int M, int N, int K, int fused) {
    const int ntn = N >> 7;
    const int tm  = blockIdx.x / ntn;
    const int tn  = blockIdx.x % ntn;

    const int tid  = threadIdx.x;
    const int wv   = tid >> 6;
    const int lane = tid & 63;
    const int col  = lane & 15;
    const int quad = lane >> 4;
    const int wm   = (wv & 1) * 64;
    const int wn   = (wv >> 1) * 64;

    __shared__ unsigned short Al[128 * LDP];
    __shared__ unsigned short Bl[128 * LDP];

    f32x4 acc[4][4];
#pragma unroll
    for (int mt = 0; mt < 4; ++mt)
#pragma unroll
        for (int nt = 0; nt < 4; ++nt) acc[mt][nt] = (f32x4){0.f, 0.f, 0.f, 0.f};

    const int i1 = tid, i2 = tid + 256;
    const size_t aoff1 = (size_t)(tm * 128 + (i1 >> 2)) * K + (i1 & 3) * 8;
    const size_t aoff2 = (size_t)(tm * 128 + (i2 >> 2)) * K + (i2 & 3) * 8;
    const size_t boff1 = (size_t)(tn * 128 + (i1 >> 2)) * K + (i1 & 3) * 8;
    const size_t boff2 = (size_t)(tn * 128 + (i2 >> 2)) * K + (i2 & 3) * 8;
    unsigned short* Aw1 = Al + (i1 >> 2) * LDP + (i1 & 3) * 8;
    unsigned short* Aw2 = Al + (i2 >> 2) * LDP + (i2 & 3) * 8;
    unsigned short* Bw1 = Bl + (i1 >> 2) * LDP + (i1 & 3) * 8;
    unsigned short* Bw2 = Bl + (i2 >> 2) * LDP + (i2 & 3) * 8;

    const unsigned short* Ab16 = (const unsigned short*)Av;
    const float*          Af   = (const float*)Av;

    uint4  a1u, a2u, b1u, b2u;
    float4 a1lo, a1hi, a2lo, a2hi;

    auto loadAB = [&](int kk) {
        if constexpr (A_BF) {
            a1u = *(const uint4*)(Ab16 + aoff1 + kk);
            a2u = *(const uint4*)(Ab16 + aoff2 + kk);
        } else {
            a1lo = *(const float4*)(Af + aoff1 + kk);
            a1hi = *(const float4*)(Af + aoff1 + kk + 4);
            a2lo = *(const float4*)(Af + aoff2 + kk);
            a2hi = *(const float4*)(Af + aoff2 + kk + 4);
        }
        b1u = *(const uint4*)(Bt + boff1 + kk);
        b2u = *(const uint4*)(Bt + boff2 + kk);
    };

    loadAB(0);

    for (int k0 = 0; k0 < K; k0 += 32) {
        __syncthreads();
        if constexpr (A_BF) {
            *(uint4*)Aw1 = a1u;
            *(uint4*)Aw2 = a2u;
        } else {
            *(bf16x8*)Aw1 = pack8(a1lo, a1hi);
            *(bf16x8*)Aw2 = pack8(a2lo, a2hi);
        }
        *(uint4*)Bw1 = b1u;
        *(uint4*)Bw2 = b2u;
        __syncthreads();

        const int kn = (k0 + 32 < K) ? k0 + 32 : k0;
        loadAB(kn);

        bf16x8 af[4], bfv[4];
#pragma unroll
        for (int t = 0; t < 4; ++t) {
            af[t]  = *(const bf16x8*)(Al + (wm + t * 16 + col) * LDP + quad * 8);
            bfv[t] = *(const bf16x8*)(Bl + (wn + t * 16 + col) * LDP + quad * 8);
        }
#pragma unroll
        for (int mt = 0; mt < 4; ++mt)
#pragma unroll
            for (int nt = 0; nt < 4; ++nt)
                acc[mt][nt] = MFMA16(af[mt], bfv[nt], acc[mt][nt]);
    }

    const int nb = tn * 128;
    if constexpr (OUT_F32) {
        float* Co = (float*)Cqv;
#pragma unroll
        for (int mt = 0; mt < 4; ++mt)
#pragma unroll
            for (int nt = 0; nt < 4; ++nt)
#pragma unroll
                for (int r = 0; r < 4; ++r) {
                    const int row = tm * 128 + wm + mt * 16 + quad * 4 + r;
                    const int cc  = nb + wn + nt * 16 + col;
                    Co[(size_t)row * N + cc] = acc[mt][nt][r];
                }
    } else {
        unsigned short* Cb;
        int ldc, nc0;
        if (!fused)         { Cb = (unsigned short*)Cqv; ldc = N;    nc0 = nb;        }
        else if (nb < 2048) { Cb = (unsigned short*)Cqv; ldc = 2048; nc0 = nb;        }
        else if (nb < 2560) { Cb = Ck;                   ldc = 512;  nc0 = nb - 2048; }
        else                { Cb = Cv;                   ldc = 512;  nc0 = nb - 2560; }
#pragma unroll
        for (int mt = 0; mt < 4; ++mt)
#pragma unroll
            for (int nt = 0; nt < 4; ++nt)
#pragma unroll
                for (int r = 0; r < 4; ++r) {
                    const int row = tm * 128 + wm + mt * 16 + quad * 4 + r;
                    const int cc  = nc0 + wn + nt * 16 + col;
                    Cb[(size_t)row * ldc + cc] = f2bf(acc[mt][nt][r]);
                }
    }
}

// ---------------------------------------------------------------------------
// Fused per-head RMSNorm + RoPE. oscale folds log2(e)/sqrt(H) into Q so the
// flash kernel's scores come out pre-scaled for the exp2-domain softmax.
// ---------------------------------------------------------------------------
__global__ void norm_rope(unsigned short* __restrict__ buf,
                          const float* __restrict__ w,
                          const float* __restrict__ cosb,
                          const float* __restrict__ sinb,
                          int nheads, float oscale) {
    const int idx = blockIdx.x;
    const int h   = idx % nheads;
    const int bt  = idx / nheads;
    const int t   = bt % T_;
    unsigned short* row = buf + ((size_t)bt * nheads + h) * H_;
    const int l = threadIdx.x;  // 0..63

    const float x0 = bf2f(row[l]);
    const float x1 = bf2f(row[l + 64]);
    float ss = x0 * x0 + x1 * x1;
#pragma unroll
    for (int off = 32; off; off >>= 1) ss += __shfl_xor(ss, off);
    const float r = rsqrtf(ss * (1.0f / 128.0f) + 1e-6f) * oscale;

    const float n0 = x0 * r * w[l];
    const float n1 = x1 * r * w[l + 64];
    const float c0 = cosb[t * H_ + l];
    const float c1 = cosb[t * H_ + l + 64];
    const float s0 = sinb[t * H_ + l];
    const float s1 = sinb[t * H_ + l + 64];

    row[l]      = f2bf(n0 * c0 - n1 * s0);
    row[l + 64] = f2bf(n1 * c1 + n0 * s1);
}

// ---------------------------------------------------------------------------
// MFMA flash attention v8 = v6 (verified 107us) + two fixes from the v7
// post-mortem:
//   1) __launch_bounds__(512,1): grid==256 blocks on 256 CUs -> only 1 block/
//      CU ever runs; the old (512,2) capped VGPRs at 128 (v6 sat exactly at
//      the cap) for zero occupancy benefit. 512-thread block still bounds the
//      allocator at 256 VGPRs (2 waves/SIMD must fit) -> no spill risk.
//   2) V double-buffered in LDS -> ONE barrier per iteration (was 2):
//      iter i: barrier (publishes buf[i&1]) -> issueV(i+1) -> compute chunk i
//      from buf[i&1] -> writeV into buf[(i+1)&1]. Reads of a buffer always
//      precede, and its next writes always follow, the same barrier.
//   K direct-to-reg (v6), swapped QK^T, in-lane softmax, defer-max, pair-
//   split + in-LDS merge all unchanged.
// LDS: V 2 groups x 2 bufs x 18432 = 73728; P 8x4608 = 36864; alf 1024.
// Total 111616 B; merge scratch aliases the dead V region.
// ---------------------------------------------------------------------------
__global__ __launch_bounds__(512, 1) void flash_attn(
    const unsigned short* __restrict__ qbuf,
    const unsigned short* __restrict__ kbuf,
    const unsigned short* __restrict__ vbuf,
    unsigned short* __restrict__ ctx) {
    const int blk = blockIdx.x;            // 256 blocks
    const int p   = blk & 7;               // pair: tiles p and 15-p
    const int h   = (blk >> 3) & 15;
    const int b   = blk >> 7;
    const int kvh = h >> 2;
    const int qtB = 15 - p;

    const int tid  = threadIdx.x;
    const int wave = tid >> 6;             // 0..7
    const int g    = wave >> 2;            // 0 = group A, 1 = group B
    const int gw   = wave & 3;             // wave-in-group
    const int lane = tid & 63;
    const int col  = lane & 15;
    const int quad = lane >> 4;
    const int gtid = gw * 64 + lane;       // 0..255 within group

    int w0 = (g ? qtB : p) * 128 + gw * 32;   // active 32 q-rows
    const int ph1 = 2 * p + 2;                // group A's own-tile chunk count

    __shared__ __align__(16) unsigned char smem[111616];
    // V double buffers: [g][d] at smem + (g*2+d)*18432, each [128][72] u16
    unsigned short* Pw   = (unsigned short*)(smem + 73728) + wave * 2304; // [32][72]
    float*          alfw = (float*)(smem + 110592) + wave * 32;           // [32]

    // Q fragments for active rows, pre-scaled by log2(e)/sqrt(H)
    bf16x8 qf[2][4];
    auto loadQ = [&]() {
#pragma unroll
        for (int nt = 0; nt < 2; ++nt)
#pragma unroll
            for (int ks = 0; ks < 4; ++ks) {
                const size_t off =
                    ((size_t)(b * T_ + w0 + nt * 16 + col) * NQ_ + h) * H_ + ks * 32 + quad * 8;
                qf[nt][ks] = *(const bf16x8*)(qbuf + off);
            }
    };
    loadQ();

    f32x4 O[2][8];
#pragma unroll
    for (int pt = 0; pt < 2; ++pt)
#pragma unroll
        for (int dt = 0; dt < 8; ++dt) O[pt][dt] = (f32x4){0.f, 0.f, 0.f, 0.f};
    float m_run[2] = {-3.0e38f, -3.0e38f};
    float l_run[2] = {0.f, 0.f};

    // ---- K direct-to-register ----
    bf16x8 kf[4][4];  // [mt][ks]
    const unsigned short* kb = kbuf + ((size_t)(b * T_) * NKV_ + kvh) * H_;
    const int koff = col * (NKV_ * H_) + quad * 8;
    auto loadK = [&](int j0) {
#pragma unroll
        for (int mt = 0; mt < 4; ++mt) {
            const unsigned short* kr = kb + (size_t)((j0 + mt * 16) * (NKV_ * H_) + koff);
#pragma unroll
            for (int ks = 0; ks < 4; ++ks)
                kf[mt][ks] = *(const bf16x8*)(kr + ks * 32);
        }
    };

    // ---- V staging (reg-staged, double-buffered) ----
    uint4 va[4];
    const size_t kvstride = (size_t)NKV_ * H_;
    auto issueV = [&](int j0) {
#pragma unroll
        for (int it = 0; it < 2; ++it) {
            const int idx = it * 256 + gtid;  // 0..511
            const int kp  = idx & 31;
            const int dc  = idx >> 5;
            const size_t g0 = ((size_t)(b * T_ + j0 + 2 * kp) * NKV_ + kvh) * H_ + dc * 8;
            va[2 * it]     = *(const uint4*)(vbuf + g0);
            va[2 * it + 1] = *(const uint4*)(vbuf + g0 + kvstride);
        }
    };
    auto writeV = [&](int d) {
        unsigned* Vw = (unsigned*)(smem + (g * 2 + d) * 18432);
#pragma unroll
        for (int it = 0; it < 2; ++it) {
            const int idx = it * 256 + gtid;
            const int kp  = idx & 31;
            const int dc  = idx >> 5;
            const uint4 v0 = va[2 * it];
            const uint4 v1 = va[2 * it + 1];
            const int wb = dc * 288 + kp;
            Vw[wb + 0 * 36] = (v0.x & 0xFFFFu) | (v1.x << 16);
            Vw[wb + 1 * 36] = (v0.x >> 16)     | (v1.x & 0xFFFF0000u);
            Vw[wb + 2 * 36] = (v0.y & 0xFFFFu) | (v1.y << 16);
            Vw[wb + 3 * 36] = (v0.y >> 16)     | (v1.y & 0xFFFF0000u);
            Vw[wb + 4 * 36] = (v0.z & 0xFFFFu) | (v1.z << 16);
            Vw[wb + 5 * 36] = (v0.z >> 16)     | (v1.z & 0xFFFF0000u);
            Vw[wb + 6 * 36] = (v0.w & 0xFFFFu) | (v1.w << 16);
            Vw[wb + 7 * 36] = (v0.w >> 16)     | (v1.w & 0xFFFF0000u);
        }
    };

    // tile-A epilogue (group A only, per-wave, no barriers)
    auto storeOut = [&]() {
        if (quad == 0) {
            alfw[col]      = 1.0f / l_run[0];
            alfw[col + 16] = 1.0f / l_run[1];
        }
        const f32x4 i0 = *(const f32x4*)&alfw[quad * 4];
        const f32x4 i1 = *(const f32x4*)&alfw[quad * 4 + 16];
#pragma unroll
        for (int pt = 0; pt < 2; ++pt)
#pragma unroll
            for (int r = 0; r < 4; ++r) {
                const float inv = pt ? i1[r] : i0[r];
                const int ig = w0 + pt * 16 + quad * 4 + r;
                unsigned short* op = ctx + ((size_t)(b * T_ + ig) * NQ_ + h) * H_;
#pragma unroll
                for (int dt = 0; dt < 8; ++dt)
                    op[dt * 16 + col] = f2bf(O[pt][dt][r] * inv);
            }
    };

    // group chunk schedule: B: 0..16; A: 0..ph1-1 (own), then 17..(31-2p)
    auto chunk_of = [&](int i) { return g ? i : (i < ph1 ? i : i + 15 - 2 * p); };

    loadK(0);
    issueV(0);
    writeV(0);  // prologue stage into buf0 (one-time full-latency wait)

    for (int i = 0; i < 17; ++i) {
        const int j0 = chunk_of(i) * 64;
        __syncthreads();  // publishes buf[i&1]; prior reads of buf[(i+1)&1] done

        if (i + 1 < 17) issueV(chunk_of(i + 1) * 64);  // lands under compute

        // group A: transition from own tile to B-tile partial
        if (g == 0 && i == ph1) {
            storeOut();  // tile p is complete -> ctx
#pragma unroll
            for (int pt = 0; pt < 2; ++pt)
#pragma unroll
                for (int dt = 0; dt < 8; ++dt) O[pt][dt] = (f32x4){0.f, 0.f, 0.f, 0.f};
            m_run[0] = m_run[1] = -3.0e38f;
            l_run[0] = l_run[1] = 0.f;
            w0 = qtB * 128 + gw * 32;
            loadQ();
        }

        const bool act = (j0 <= w0 + 31);  // this wave has unmasked keys here

        // ---- swapped QK^T: St[key-tile][q-tile], 32 MFMAs, operands in regs ----
        f32x4 St[4][2];
        if (act) {
#pragma unroll
            for (int mt = 0; mt < 4; ++mt)
#pragma unroll
                for (int nt = 0; nt < 2; ++nt) St[mt][nt] = (f32x4){0.f, 0.f, 0.f, 0.f};
#pragma unroll
            for (int ks = 0; ks < 4; ++ks)
#pragma unroll
                for (int mt = 0; mt < 4; ++mt) {
                    St[mt][0] = MFMA16(kf[mt][ks], qf[0][ks], St[mt][0]);
                    St[mt][1] = MFMA16(kf[mt][ks], qf[1][ks], St[mt][1]);
                }

            // ---- mask (acc row = key, col = query) ----
            const bool needmask = (j0 + 63 > w0);
            if (needmask) {
                const int ig0 = w0 + col;
#pragma unroll
                for (int mt = 0; mt < 4; ++mt)
#pragma unroll
                    for (int r = 0; r < 4; ++r) {
                        const int key = j0 + mt * 16 + quad * 4 + r;
                        if (key > ig0)      St[mt][0][r] = -3.0e38f;
                        if (key > ig0 + 16) St[mt][1][r] = -3.0e38f;
                    }
            }

            // ---- in-lane row max ----
            float rm[2];
#pragma unroll
            for (int nt = 0; nt < 2; ++nt) {
                float m0 = fmaxf(fmaxf(St[0][nt][0], St[0][nt][1]),
                                 fmaxf(St[0][nt][2], St[0][nt][3]));
#pragma unroll
                for (int mt = 1; mt < 4; ++mt)
                    m0 = fmaxf(m0, fmaxf(fmaxf(St[mt][nt][0], St[mt][nt][1]),
                                         fmaxf(St[mt][nt][2], St[mt][nt][3])));
                m0 = fmaxf(m0, __shfl_xor(m0, 16));
                m0 = fmaxf(m0, __shfl_xor(m0, 32));
                rm[nt] = m0;
            }

            // ---- defer-max (THR=8, exp2 domain) ----
            const int defer = __all((rm[0] <= m_run[0] + 8.0f) && (rm[1] <= m_run[1] + 8.0f));
            if (!defer) {
                const float mn0 = fmaxf(m_run[0], rm[0]);
                const float mn1 = fmaxf(m_run[1], rm[1]);
                const float al0 = exp2f(m_run[0] - mn0);
                const float al1 = exp2f(m_run[1] - mn1);
                m_run[0] = mn0; m_run[1] = mn1;
                l_run[0] *= al0; l_run[1] *= al1;
                if (quad == 0) { alfw[col] = al0; alfw[col + 16] = al1; }
            }

            // ---- P = exp2(S - m), in-lane sum, b64 packed writes ----
            float ls0 = 0.f, ls1 = 0.f;
#pragma unroll
            for (int mt = 0; mt < 4; ++mt) {
                const float p0 = exp2f(St[mt][0][0] - m_run[0]);
                const float p1 = exp2f(St[mt][0][1] - m_run[0]);
                const float p2 = exp2f(St[mt][0][2] - m_run[0]);
                const float p3 = exp2f(St[mt][0][3] - m_run[0]);
                ls0 += (p0 + p1) + (p2 + p3);
                *(uint2*)(Pw + col * 72 + mt * 16 + quad * 4) =
                    make_uint2((unsigned)f2bf(p0) | ((unsigned)f2bf(p1) << 16),
                               (unsigned)f2bf(p2) | ((unsigned)f2bf(p3) << 16));
                const float q0 = exp2f(St[mt][1][0] - m_run[1]);
                const float q1 = exp2f(St[mt][1][1] - m_run[1]);
                const float q2 = exp2f(St[mt][1][2] - m_run[1]);
                const float q3 = exp2f(St[mt][1][3] - m_run[1]);
                ls1 += (q0 + q1) + (q2 + q3);
                *(uint2*)(Pw + (col + 16) * 72 + mt * 16 + quad * 4) =
                    make_uint2((unsigned)f2bf(q0) | ((unsigned)f2bf(q1) << 16),
                               (unsigned)f2bf(q2) | ((unsigned)f2bf(q3) << 16));
            }
            ls0 += __shfl_xor(ls0, 16); ls0 += __shfl_xor(ls0, 32);
            ls1 += __shfl_xor(ls1, 16); ls1 += __shfl_xor(ls1, 32);
            l_run[0] += ls0; l_run[1] += ls1;

            // ---- O rescale (only when not deferred) ----
            if (!defer) {
                const f32x4 a0 = *(const f32x4*)&alfw[quad * 4];
                const f32x4 a1 = *(const f32x4*)&alfw[quad * 4 + 16];
#pragma unroll
                for (int dt = 0; dt < 8; ++dt)
#pragma unroll
                    for (int r = 0; r < 4; ++r) { O[0][dt][r] *= a0[r]; O[1][dt][r] *= a1[r]; }
            }
        }

        // refill kf for next chunk (kf dead after QK; PV below hides latency)
        if (i + 1 < 17) loadK(chunk_of(i + 1) * 64);

        if (act) {
            // ---- PV: O += P(32x64) @ V(64x128), 32 MFMAs, V from buf[i&1] ----
            const unsigned short* Vg = (const unsigned short*)(smem + (g * 2 + (i & 1)) * 18432);
#pragma unroll
            for (int ks = 0; ks < 2; ++ks) {
                const bf16x8 pa0 = *(const bf16x8*)(Pw + col * 72 + ks * 32 + quad * 8);
                const bf16x8 pa1 = *(const bf16x8*)(Pw + (col + 16) * 72 + ks * 32 + quad * 8);
#pragma unroll
                for (int dt = 0; dt < 8; ++dt) {
                    const bf16x8 vf = *(const bf16x8*)(Vg + (dt * 16 + col) * 72 + ks * 32 + quad * 8);
                    O[0][dt] = MFMA16(pa0, vf, O[0][dt]);
                    O[1][dt] = MFMA16(pa1, vf, O[1][dt]);
                }
            }
        }

        // stage next chunk's V into the other buffer (published by next barrier)
        if (i + 1 < 17) writeV((i + 1) & 1);
    }

    // ---- merge: combine B-tile partials (A: keys >= 1088, B: keys < 1088) ----
    __syncthreads();  // all compute/LDS reads done; V region reusable
    float* mlA = (float*)(smem + 65536);  // [4][32][2]
    float* mlB = (float*)(smem + 66560);  // [4][32][2]
    if (g == 0) {
        float* Of = (float*)smem + gw * 4096;  // [32][128] raw O
        float* ml = mlA + gw * 64;
        if (quad == 0) {
            ml[2 * col]            = m_run[0]; ml[2 * col + 1]        = l_run[0];
            ml[2 * (col + 16)]     = m_run[1]; ml[2 * (col + 16) + 1] = l_run[1];
        }
#pragma unroll
        for (int pt = 0; pt < 2; ++pt)
#pragma unroll
            for (int dt = 0; dt < 8; ++dt)
#pragma unroll
                for (int r = 0; r < 4; ++r)
                    Of[(pt * 16 + quad * 4 + r) * 128 + dt * 16 + col] = O[pt][dt][r];
    }
    __syncthreads();
    if (g == 1) {
        float* Of = (float*)smem + gw * 4096;
        float* mA = mlA + gw * 64;
        float* mB = mlB + gw * 64;
        if (quad == 0) {
            mB[2 * col]            = m_run[0]; mB[2 * col + 1]        = l_run[0];
            mB[2 * (col + 16)]     = m_run[1]; mB[2 * (col + 16) + 1] = l_run[1];
        }
#pragma unroll
        for (int pt = 0; pt < 2; ++pt)
#pragma unroll
            for (int r = 0; r < 4; ++r) {
                const int row = pt * 16 + quad * 4 + r;
                const float mBv = mB[2 * row], lBv = mB[2 * row + 1];
                const float mAv = mA[2 * row], lAv = mA[2 * row + 1];
                const float m  = fmaxf(mAv, mBv);
                const float aB = exp2f(mBv - m);
                const float aA = exp2f(mAv - m);
                const float inv = 1.0f / (lBv * aB + lAv * aA);
                const int ig = w0 + row;
                unsigned short* op = ctx + ((size_t)(b * T_ + ig) * NQ_ + h) * H_;
#pragma unroll
                for (int dt = 0; dt < 8; ++dt)
                    op[dt * 16 + col] =
                        f2bf((O[pt][dt][r] * aB + Of[row * 128 + dt * 16 + col] * aA) * inv);
            }
    }
}

// ---------------------------------------------------------------------------
extern "C" void kernel_launch(void* const* d_in, const int* in_sizes, int n_in,
                              void* d_out, int out_size, void* d_ws, size_t ws_size,
                              hipStream_t stream) {
    const float* x    = (const float*)d_in[0];
    const float* Wq   = (const float*)d_in[1];
    const float* Wk   = (const float*)d_in[2];
    const float* Wv   = (const float*)d_in[3];
    const float* Wo   = (const float*)d_in[4];
    const float* qnw  = (const float*)d_in[5];
    const float* knw  = (const float*)d_in[6];
    const float* cosb = (const float*)d_in[7];
    const float* sinb = (const float*)d_in[8];
    // d_in[9] = attn_mask: exact causal tril(0/-1e9) -> implemented directly

    const int M = B_ * T_;  // 4096
    // ws layout (u16 offsets), 42 MB proven footprint:
    //   WqT/WkT/WvT [0,6291456) dead after QKV; ctx [0,8388608) aliases them
    //   q [8388608,16777216) (WoT aliases after attn); k; v
    unsigned short* ws  = (unsigned short*)d_ws;
    unsigned short* WqT = ws;
    unsigned short* WkT = WqT + (size_t)2048 * 2048;
    unsigned short* WvT = WkT + (size_t)512 * 2048;
    unsigned short* ctx = ws;
    unsigned short* q   = ws + (size_t)8388608;
    unsigned short* k   = ws + (size_t)16777216;
    unsigned short* v   = ws + (size_t)18874368;
    unsigned short* WoT = q;

    transpose_cvt<<<(2048 / 64) * (2048 / 64), 256, 0, stream>>>(Wq, WqT, 2048, 2048);
    transpose_cvt<<<(2048 / 64) * (512 / 64),  256, 0, stream>>>(Wk, WkT, 2048, 512);
    transpose_cvt<<<(2048 / 64) * (512 / 64),  256, 0, stream>>>(Wv, WvT, 2048, 512);

    gemm_bt<false, false><<<(M / 128) * (3072 / 128), 256, 0, stream>>>(
        (const void*)x, WqT, (void*)q, k, v, M, 3072, C_, 1);

    // Q pre-scaled by log2(e)/sqrt(128) for the exp2-domain softmax
    norm_rope<<<M * NQ_, 64, 0, stream>>>(q, qnw, cosb, sinb, NQ_, 0.12751743f);
    norm_rope<<<M * NKV_, 64, 0, stream>>>(k, knw, cosb, sinb, NKV_, 1.0f);

    flash_attn<<<256, 512, 0, stream>>>(q, k, v, ctx);

    transpose_cvt<<<(2048 / 64) * (2048 / 64), 256, 0, stream>>>(Wo, WoT, 2048, 2048);
    gemm_bt<true, true><<<(M / 128) * (C_ / 128), 256, 0, stream>>>(
        (const void*)ctx, WoT, d_out, nullptr, nullptr, M, C_, NQ_ * H_, 0);
}

// Round 8
// 371.285 us; speedup vs baseline: 1.4410x; 1.1457x over previous
//
#include <hip/hip_runtime.h>
#include <hip/hip_bf16.h>

// Problem: B=2, T=2048, C=2048, NQ=16, NKV=4, H=128, EPS=1e-6
// DTYPE GROUND TRUTH (established rounds 1-6): ALL inputs f32, output f32.
// Internals: bf16 (weights pre-converted; x pre-converted to bf16 in d_out).
#define B_   2
#define T_   2048
#define C_   2048
#define NQ_  16
#define NKV_ 4
#define H_   128

using bf16x8 = __attribute__((ext_vector_type(8))) short;
using f32x4  = __attribute__((ext_vector_type(4))) float;

__device__ __forceinline__ unsigned short f2bf(float f) {
    __hip_bfloat16 h = __float2bfloat16(f);  // RNE
    union { __hip_bfloat16 h; unsigned short s; } c;
    c.h = h;
    return c.s;
}
__device__ __forceinline__ float bf2f(unsigned short s) {
    return __uint_as_float(((unsigned)s) << 16);
}
__device__ __forceinline__ bf16x8 pack8(float4 f0, float4 f1) {
    bf16x8 r;
    r[0] = (short)f2bf(f0.x); r[1] = (short)f2bf(f0.y);
    r[2] = (short)f2bf(f0.z); r[3] = (short)f2bf(f0.w);
    r[4] = (short)f2bf(f1.x); r[5] = (short)f2bf(f1.y);
    r[6] = (short)f2bf(f1.z); r[7] = (short)f2bf(f1.w);
    return r;
}

#define MFMA16(a, b, c) __builtin_amdgcn_mfma_f32_16x16x32_bf16(a, b, c, 0, 0, 0)

// async global->LDS: 16B per lane, LDS dst = wave-uniform base + lane*16
__device__ __forceinline__ void gl_lds16(const void* g, void* l) {
    __builtin_amdgcn_global_load_lds(
        (const __attribute__((address_space(1))) void*)g,
        (__attribute__((address_space(3))) void*)l, 16, 0, 0);
}

// ---------------------------------------------------------------------------
// Elementwise f32 -> bf16 convert (x pre-pass; dst aliases d_out scratch).
// ---------------------------------------------------------------------------
__global__ void cvt_bf16(const float* __restrict__ src,
                         unsigned short* __restrict__ dst) {
    const int i = (blockIdx.x * 256 + threadIdx.x) * 8;
    const float4 a = *(const float4*)(src + i);
    const float4 b = *(const float4*)(src + i + 4);
    *(bf16x8*)(dst + i) = pack8(a, b);
}

// ---------------------------------------------------------------------------
// 64x64-tile transpose + f32->bf16 convert: dst[c][r] = bf16(src[r][c]).
// ---------------------------------------------------------------------------
__global__ void transpose_cvt(const float* __restrict__ src,
                              unsigned short* __restrict__ dst,
                              int R, int Cc) {
    const int tc = Cc >> 6;
    const int r0 = (blockIdx.x / tc) * 64;
    const int c0 = (blockIdx.x % tc) * 64;
    __shared__ unsigned short Tl[64 * 65];
    const int tid = threadIdx.x;
#pragma unroll
    for (int it = 0; it < 16; ++it) {
        const int idx = it * 256 + tid;
        const int r = idx >> 6, c = idx & 63;
        Tl[c * 65 + r] = f2bf(src[(size_t)(r0 + r) * Cc + c0 + c]);
    }
    __syncthreads();
#pragma unroll
    for (int it = 0; it < 16; ++it) {
        const int idx = it * 256 + tid;
        const int c = idx >> 6, r = idx & 63;
        dst[(size_t)(c0 + c) * R + r0 + r] = Tl[c * 65 + r];
    }
}

// ---------------------------------------------------------------------------
// 128x128-tile GEMM v2 (m97-style): C = A @ Bt^T, A and B both bf16 K-major.
//   * global_load_lds 16B staging (no VGPR round-trip, no staging VALU).
//   * Linear LDS [128][32] per tile with source-side XOR granule swizzle
//     (granule ^= row&3); reads apply the same XOR -> ~2-way-max conflicts
//     on ds_read_b128 (free per m136).
//   * XCD-aware blockIdx swizzle (T1; nwg % 8 == 0 for both call sites).
//   Fused-QKV epilogue (q/k/v split) and f32 epilogue unchanged.
// LDS = 2 x 8192 B = 16 KiB -> 2 blocks/CU at (256,2).
// ---------------------------------------------------------------------------
template <bool OUT_F32>
__global__ __launch_bounds__(256, 2) void gemm_bt(
    const unsigned short* __restrict__ Ab,
    const unsigned short* __restrict__ Bt,
    void* __restrict__ Cqv,
    unsigned short* __restrict__ Ck,
    unsigned short* __restrict__ Cv,
    int M, int N, int K, int fused) {
    const int ntn = N >> 7;
    const int cpx = gridDim.x >> 3;                       // nwg % 8 == 0
    const int wg  = (blockIdx.x & 7) * cpx + (blockIdx.x >> 3);
    const int tm  = wg / ntn;
    const int tn  = wg % ntn;

    const int tid  = threadIdx.x;
    const int wv   = tid >> 6;
    const int lane = tid & 63;
    const int col  = lane & 15;
    const int quad = lane >> 4;
    const int wm   = (wv & 1) * 64;
    const int wn   = (wv >> 1) * 64;

    __shared__ unsigned short Al[128 * 32];
    __shared__ unsigned short Bl[128 * 32];

    f32x4 acc[4][4];
#pragma unroll
    for (int mt = 0; mt < 4; ++mt)
#pragma unroll
        for (int nt = 0; nt < 4; ++nt) acc[mt][nt] = (f32x4){0.f, 0.f, 0.f, 0.f};

    // staging addresses: wave wv covers rows [wv*32, wv*32+32) in 2 slabs of 16
    const int rsl = lane >> 2;                 // 0..15 row within slab
    const int gsw = ((lane & 3) ^ (rsl & 3)) << 3;  // XOR-swizzled granule (u16)
    const int row0 = wv * 32 + rsl;
    const int row1 = row0 + 16;
    const size_t aoff0 = (size_t)(tm * 128 + row0) * K + gsw;
    const size_t aoff1 = (size_t)(tm * 128 + row1) * K + gsw;
    const size_t boff0 = (size_t)(tn * 128 + row0) * K + gsw;
    const size_t boff1 = (size_t)(tn * 128 + row1) * K + gsw;
    unsigned short* Ad0 = Al + (wv * 32) * 32;       // wave-uniform LDS bases
    unsigned short* Ad1 = Al + (wv * 32 + 16) * 32;
    unsigned short* Bd0 = Bl + (wv * 32) * 32;
    unsigned short* Bd1 = Bl + (wv * 32 + 16) * 32;

    const int swq = (quad ^ (col & 3)) << 3;   // read-side XOR (u16 offset)

    for (int k0 = 0; k0 < K; k0 += 32) {
        __syncthreads();  // prior compute's LDS reads complete
        gl_lds16(Ab + aoff0 + k0, Ad0);
        gl_lds16(Ab + aoff1 + k0, Ad1);
        gl_lds16(Bt + boff0 + k0, Bd0);
        gl_lds16(Bt + boff1 + k0, Bd1);
        __syncthreads();  // vmcnt drained -> staged tile visible

        bf16x8 af[4], bfv[4];
#pragma unroll
        for (int t = 0; t < 4; ++t) {
            af[t]  = *(const bf16x8*)(Al + (wm + t * 16 + col) * 32 + swq);
            bfv[t] = *(const bf16x8*)(Bl + (wn + t * 16 + col) * 32 + swq);
        }
#pragma unroll
        for (int mt = 0; mt < 4; ++mt)
#pragma unroll
            for (int nt = 0; nt < 4; ++nt)
                acc[mt][nt] = MFMA16(af[mt], bfv[nt], acc[mt][nt]);
    }

    const int nb = tn * 128;
    if constexpr (OUT_F32) {
        float* Co = (float*)Cqv;
#pragma unroll
        for (int mt = 0; mt < 4; ++mt)
#pragma unroll
            for (int nt = 0; nt < 4; ++nt)
#pragma unroll
                for (int r = 0; r < 4; ++r) {
                    const int row = tm * 128 + wm + mt * 16 + quad * 4 + r;
                    const int cc  = nb + wn + nt * 16 + col;
                    Co[(size_t)row * N + cc] = acc[mt][nt][r];
                }
    } else {
        unsigned short* Cb;
        int ldc, nc0;
        if (!fused)         { Cb = (unsigned short*)Cqv; ldc = N;    nc0 = nb;        }
        else if (nb < 2048) { Cb = (unsigned short*)Cqv; ldc = 2048; nc0 = nb;        }
        else if (nb < 2560) { Cb = Ck;                   ldc = 512;  nc0 = nb - 2048; }
        else                { Cb = Cv;                   ldc = 512;  nc0 = nb - 2560; }
#pragma unroll
        for (int mt = 0; mt < 4; ++mt)
#pragma unroll
            for (int nt = 0; nt < 4; ++nt)
#pragma unroll
                for (int r = 0; r < 4; ++r) {
                    const int row = tm * 128 + wm + mt * 16 + quad * 4 + r;
                    const int cc  = nc0 + wn + nt * 16 + col;
                    Cb[(size_t)row * ldc + cc] = f2bf(acc[mt][nt][r]);
                }
    }
}

// ---------------------------------------------------------------------------
// Fused per-head RMSNorm + RoPE. oscale folds log2(e)/sqrt(H) into Q so the
// flash kernel's scores come out pre-scaled for the exp2-domain softmax.
// ---------------------------------------------------------------------------
__global__ void norm_rope(unsigned short* __restrict__ buf,
                          const float* __restrict__ w,
                          const float* __restrict__ cosb,
                          const float* __restrict__ sinb,
                          int nheads, float oscale) {
    const int idx = blockIdx.x;
    const int h   = idx % nheads;
    const int bt  = idx / nheads;
    const int t   = bt % T_;
    unsigned short* row = buf + ((size_t)bt * nheads + h) * H_;
    const int l = threadIdx.x;  // 0..63

    const float x0 = bf2f(row[l]);
    const float x1 = bf2f(row[l + 64]);
    float ss = x0 * x0 + x1 * x1;
#pragma unroll
    for (int off = 32; off; off >>= 1) ss += __shfl_xor(ss, off);
    const float r = rsqrtf(ss * (1.0f / 128.0f) + 1e-6f) * oscale;

    const float n0 = x0 * r * w[l];
    const float n1 = x1 * r * w[l + 64];
    const float c0 = cosb[t * H_ + l];
    const float c1 = cosb[t * H_ + l + 64];
    const float s0 = sinb[t * H_ + l];
    const float s1 = sinb[t * H_ + l + 64];

    row[l]      = f2bf(n0 * c0 - n1 * s0);
    row[l + 64] = f2bf(n1 * c1 + n0 * s1);
}

// ---------------------------------------------------------------------------
// MFMA flash attention v6 (VERIFIED 107us, round 5) — restored verbatim.
//   KV-split pair schedule + in-LDS merge; K direct-to-registers; V staged
//   via regs->LDS with packed-transpose layout; swapped QK^T; in-lane
//   softmax; defer-max. 2 barriers/iteration (1-barrier variant measured
//   slower, round 7).
// LDS = 36864(V) + 36864(P) + 1024(alf) + 2048(ml) = 76800 B.
// ---------------------------------------------------------------------------
__global__ __launch_bounds__(512, 2) void flash_attn(
    const unsigned short* __restrict__ qbuf,
    const unsigned short* __restrict__ kbuf,
    const unsigned short* __restrict__ vbuf,
    unsigned short* __restrict__ ctx) {
    const int blk = blockIdx.x;            // 256 blocks
    const int p   = blk & 7;               // pair: tiles p and 15-p
    const int h   = (blk >> 3) & 15;
    const int b   = blk >> 7;
    const int kvh = h >> 2;
    const int qtB = 15 - p;

    const int tid  = threadIdx.x;
    const int wave = tid >> 6;             // 0..7
    const int g    = wave >> 2;            // 0 = group A, 1 = group B
    const int gw   = wave & 3;             // wave-in-group
    const int lane = tid & 63;
    const int col  = lane & 15;
    const int quad = lane >> 4;
    const int gtid = gw * 64 + lane;       // 0..255 within group

    int w0 = (g ? qtB : p) * 128 + gw * 32;   // active 32 q-rows
    const int ph1 = 2 * p + 2;                // group A's own-tile chunk count

    __shared__ __align__(16) unsigned char smem[76800];
    unsigned short* Vg   = (unsigned short*)smem + g * 9216;              // [128][72]
    unsigned short* Pw   = (unsigned short*)(smem + 36864) + wave * 2304; // [32][72]
    float*          alfw = (float*)(smem + 73728) + wave * 32;            // [32]
    unsigned*       Vw   = (unsigned*)Vg;

    // Q fragments for active rows, pre-scaled by log2(e)/sqrt(H)
    bf16x8 qf[2][4];
    auto loadQ = [&]() {
#pragma unroll
        for (int nt = 0; nt < 2; ++nt)
#pragma unroll
            for (int ks = 0; ks < 4; ++ks) {
                const size_t off =
                    ((size_t)(b * T_ + w0 + nt * 16 + col) * NQ_ + h) * H_ + ks * 32 + quad * 8;
                qf[nt][ks] = *(const bf16x8*)(qbuf + off);
            }
    };
    loadQ();

    f32x4 O[2][8];
#pragma unroll
    for (int pt = 0; pt < 2; ++pt)
#pragma unroll
        for (int dt = 0; dt < 8; ++dt) O[pt][dt] = (f32x4){0.f, 0.f, 0.f, 0.f};
    float m_run[2] = {-3.0e38f, -3.0e38f};
    float l_run[2] = {0.f, 0.f};

    // ---- K direct-to-register ----
    bf16x8 kf[4][4];  // [mt][ks]
    const unsigned short* kb = kbuf + ((size_t)(b * T_) * NKV_ + kvh) * H_;
    const int koff = col * (NKV_ * H_) + quad * 8;
    auto loadK = [&](int j0) {
#pragma unroll
        for (int mt = 0; mt < 4; ++mt) {
            const unsigned short* kr = kb + (size_t)((j0 + mt * 16) * (NKV_ * H_) + koff);
#pragma unroll
            for (int ks = 0; ks < 4; ++ks)
                kf[mt][ks] = *(const bf16x8*)(kr + ks * 32);
        }
    };

    // ---- V staging (reg-staged, T14) ----
    uint4 va[4];
    const size_t kvstride = (size_t)NKV_ * H_;
    auto issueV = [&](int j0) {
#pragma unroll
        for (int it = 0; it < 2; ++it) {
            const int idx = it * 256 + gtid;  // 0..511
            const int kp  = idx & 31;
            const int dc  = idx >> 5;
            const size_t g0 = ((size_t)(b * T_ + j0 + 2 * kp) * NKV_ + kvh) * H_ + dc * 8;
            va[2 * it]     = *(const uint4*)(vbuf + g0);
            va[2 * it + 1] = *(const uint4*)(vbuf + g0 + kvstride);
        }
    };
    auto writeV = [&]() {
#pragma unroll
        for (int it = 0; it < 2; ++it) {
            const int idx = it * 256 + gtid;
            const int kp  = idx & 31;
            const int dc  = idx >> 5;
            const uint4 v0 = va[2 * it];
            const uint4 v1 = va[2 * it + 1];
            const int wb = dc * 288 + kp;
            Vw[wb + 0 * 36] = (v0.x & 0xFFFFu) | (v1.x << 16);
            Vw[wb + 1 * 36] = (v0.x >> 16)     | (v1.x & 0xFFFF0000u);
            Vw[wb + 2 * 36] = (v0.y & 0xFFFFu) | (v1.y << 16);
            Vw[wb + 3 * 36] = (v0.y >> 16)     | (v1.y & 0xFFFF0000u);
            Vw[wb + 4 * 36] = (v0.z & 0xFFFFu) | (v1.z << 16);
            Vw[wb + 5 * 36] = (v0.z >> 16)     | (v1.z & 0xFFFF0000u);
            Vw[wb + 6 * 36] = (v0.w & 0xFFFFu) | (v1.w << 16);
            Vw[wb + 7 * 36] = (v0.w >> 16)     | (v1.w & 0xFFFF0000u);
        }
    };

    // tile-A epilogue (group A only, no barriers inside)
    auto storeOut = [&]() {
        if (quad == 0) {
            alfw[col]      = 1.0f / l_run[0];
            alfw[col + 16] = 1.0f / l_run[1];
        }
        const f32x4 i0 = *(const f32x4*)&alfw[quad * 4];
        const f32x4 i1 = *(const f32x4*)&alfw[quad * 4 + 16];
#pragma unroll
        for (int pt = 0; pt < 2; ++pt)
#pragma unroll
            for (int r = 0; r < 4; ++r) {
                const float inv = pt ? i1[r] : i0[r];
                const int ig = w0 + pt * 16 + quad * 4 + r;
                unsigned short* op = ctx + ((size_t)(b * T_ + ig) * NQ_ + h) * H_;
#pragma unroll
                for (int dt = 0; dt < 8; ++dt)
                    op[dt * 16 + col] = f2bf(O[pt][dt][r] * inv);
            }
    };

    // group chunk schedule: B: 0..16; A: 0..ph1-1 (own), then 17..(31-2p)
    auto chunk_of = [&](int i) { return g ? i : (i < ph1 ? i : i + 15 - 2 * p); };

    loadK(0);
    issueV(0);

    for (int i = 0; i < 17; ++i) {
        const int j0 = chunk_of(i) * 64;
        __syncthreads();  // prior chunk's V/P reads complete; prefetched V landed
        writeV();
        __syncthreads();  // staged V visible

        if (i + 1 < 17) issueV(chunk_of(i + 1) * 64);

        // group A: transition from own tile to B-tile partial
        if (g == 0 && i == ph1) {
            storeOut();  // tile p is complete -> ctx
#pragma unroll
            for (int pt = 0; pt < 2; ++pt)
#pragma unroll
                for (int dt = 0; dt < 8; ++dt) O[pt][dt] = (f32x4){0.f, 0.f, 0.f, 0.f};
            m_run[0] = m_run[1] = -3.0e38f;
            l_run[0] = l_run[1] = 0.f;
            w0 = qtB * 128 + gw * 32;
            loadQ();
        }

        const bool act = (j0 <= w0 + 31);  // this wave has unmasked keys here

        // ---- swapped QK^T: St[key-tile][q-tile], 32 MFMAs, operands in regs ----
        f32x4 St[4][2];
        if (act) {
#pragma unroll
            for (int mt = 0; mt < 4; ++mt)
#pragma unroll
                for (int nt = 0; nt < 2; ++nt) St[mt][nt] = (f32x4){0.f, 0.f, 0.f, 0.f};
#pragma unroll
            for (int ks = 0; ks < 4; ++ks)
#pragma unroll
                for (int mt = 0; mt < 4; ++mt) {
                    St[mt][0] = MFMA16(kf[mt][ks], qf[0][ks], St[mt][0]);
                    St[mt][1] = MFMA16(kf[mt][ks], qf[1][ks], St[mt][1]);
                }
        }

        // refill kf for next chunk (after last use; unconditional so masked
        // waves keep the prefetch chain alive)
        if (i + 1 < 17) loadK(chunk_of(i + 1) * 64);

        if (!act) continue;

        // ---- mask (acc row = key, col = query) ----
        const bool needmask = (j0 + 63 > w0);
        if (needmask) {
            const int ig0 = w0 + col;
#pragma unroll
            for (int mt = 0; mt < 4; ++mt)
#pragma unroll
                for (int r = 0; r < 4; ++r) {
                    const int key = j0 + mt * 16 + quad * 4 + r;
                    if (key > ig0)      St[mt][0][r] = -3.0e38f;
                    if (key > ig0 + 16) St[mt][1][r] = -3.0e38f;
                }
        }

        // ---- in-lane row max ----
        float rm[2];
#pragma unroll
        for (int nt = 0; nt < 2; ++nt) {
            float m0 = fmaxf(fmaxf(St[0][nt][0], St[0][nt][1]),
                             fmaxf(St[0][nt][2], St[0][nt][3]));
#pragma unroll
            for (int mt = 1; mt < 4; ++mt)
                m0 = fmaxf(m0, fmaxf(fmaxf(St[mt][nt][0], St[mt][nt][1]),
                                     fmaxf(St[mt][nt][2], St[mt][nt][3])));
            m0 = fmaxf(m0, __shfl_xor(m0, 16));
            m0 = fmaxf(m0, __shfl_xor(m0, 32));
            rm[nt] = m0;
        }

        // ---- defer-max (THR=8, exp2 domain) ----
        const int defer = __all((rm[0] <= m_run[0] + 8.0f) && (rm[1] <= m_run[1] + 8.0f));
        if (!defer) {
            const float mn0 = fmaxf(m_run[0], rm[0]);
            const float mn1 = fmaxf(m_run[1], rm[1]);
            const float al0 = exp2f(m_run[0] - mn0);
            const float al1 = exp2f(m_run[1] - mn1);
            m_run[0] = mn0; m_run[1] = mn1;
            l_run[0] *= al0; l_run[1] *= al1;
            if (quad == 0) { alfw[col] = al0; alfw[col + 16] = al1; }
        }

        // ---- P = exp2(S - m), in-lane sum, b64 packed writes ----
        float ls0 = 0.f, ls1 = 0.f;
#pragma unroll
        for (int mt = 0; mt < 4; ++mt) {
            const float p0 = exp2f(St[mt][0][0] - m_run[0]);
            const float p1 = exp2f(St[mt][0][1] - m_run[0]);
            const float p2 = exp2f(St[mt][0][2] - m_run[0]);
            const float p3 = exp2f(St[mt][0][3] - m_run[0]);
            ls0 += (p0 + p1) + (p2 + p3);
            *(uint2*)(Pw + col * 72 + mt * 16 + quad * 4) =
                make_uint2((unsigned)f2bf(p0) | ((unsigned)f2bf(p1) << 16),
                           (unsigned)f2bf(p2) | ((unsigned)f2bf(p3) << 16));
            const float q0 = exp2f(St[mt][1][0] - m_run[1]);
            const float q1 = exp2f(St[mt][1][1] - m_run[1]);
            const float q2 = exp2f(St[mt][1][2] - m_run[1]);
            const float q3 = exp2f(St[mt][1][3] - m_run[1]);
            ls1 += (q0 + q1) + (q2 + q3);
            *(uint2*)(Pw + (col + 16) * 72 + mt * 16 + quad * 4) =
                make_uint2((unsigned)f2bf(q0) | ((unsigned)f2bf(q1) << 16),
                           (unsigned)f2bf(q2) | ((unsigned)f2bf(q3) << 16));
        }
        ls0 += __shfl_xor(ls0, 16); ls0 += __shfl_xor(ls0, 32);
        ls1 += __shfl_xor(ls1, 16); ls1 += __shfl_xor(ls1, 32);
        l_run[0] += ls0; l_run[1] += ls1;

        // ---- O rescale (only when not deferred) ----
        if (!defer) {
            const f32x4 a0 = *(const f32x4*)&alfw[quad * 4];
            const f32x4 a1 = *(const f32x4*)&alfw[quad * 4 + 16];
#pragma unroll
            for (int dt = 0; dt < 8; ++dt)
#pragma unroll
                for (int r = 0; r < 4; ++r) { O[0][dt][r] *= a0[r]; O[1][dt][r] *= a1[r]; }
        }

        // ---- PV: O += P(32x64) @ V(64x128), 32 MFMAs ----
#pragma unroll
        for (int ks = 0; ks < 2; ++ks) {
            const bf16x8 pa0 = *(const bf16x8*)(Pw + col * 72 + ks * 32 + quad * 8);
            const bf16x8 pa1 = *(const bf16x8*)(Pw + (col + 16) * 72 + ks * 32 + quad * 8);
#pragma unroll
            for (int dt = 0; dt < 8; ++dt) {
                const bf16x8 vf = *(const bf16x8*)(Vg + (dt * 16 + col) * 72 + ks * 32 + quad * 8);
                O[0][dt] = MFMA16(pa0, vf, O[0][dt]);
                O[1][dt] = MFMA16(pa1, vf, O[1][dt]);
            }
        }
    }

    // ---- merge: combine B-tile partials (A: keys >= 1088, B: keys < 1088) ----
    __syncthreads();  // all compute/LDS reads done; V/P buffers reusable
    float* mlA = (float*)(smem + 74752);  // [4][32][2]
    float* mlB = (float*)(smem + 75776);  // [4][32][2]
    if (g == 0) {
        float* Of = (float*)smem + gw * 4096;  // [32][128] raw O
        float* ml = mlA + gw * 64;
        if (quad == 0) {
            ml[2 * col]            = m_run[0]; ml[2 * col + 1]        = l_run[0];
            ml[2 * (col + 16)]     = m_run[1]; ml[2 * (col + 16) + 1] = l_run[1];
        }
#pragma unroll
        for (int pt = 0; pt < 2; ++pt)
#pragma unroll
            for (int dt = 0; dt < 8; ++dt)
#pragma unroll
                for (int r = 0; r < 4; ++r)
                    Of[(pt * 16 + quad * 4 + r) * 128 + dt * 16 + col] = O[pt][dt][r];
    }
    __syncthreads();
    if (g == 1) {
        float* Of = (float*)smem + gw * 4096;
        float* mA = mlA + gw * 64;
        float* mB = mlB + gw * 64;
        if (quad == 0) {
            mB[2 * col]            = m_run[0]; mB[2 * col + 1]        = l_run[0];
            mB[2 * (col + 16)]     = m_run[1]; mB[2 * (col + 16) + 1] = l_run[1];
        }
#pragma unroll
        for (int pt = 0; pt < 2; ++pt)
#pragma unroll
            for (int r = 0; r < 4; ++r) {
                const int row = pt * 16 + quad * 4 + r;
                const float mBv = mB[2 * row], lBv = mB[2 * row + 1];
                const float mAv = mA[2 * row], lAv = mA[2 * row + 1];
                const float m  = fmaxf(mAv, mBv);
                const float aB = exp2f(mBv - m);
                const float aA = exp2f(mAv - m);
                const float inv = 1.0f / (lBv * aB + lAv * aA);
                const int ig = w0 + row;
                unsigned short* op = ctx + ((size_t)(b * T_ + ig) * NQ_ + h) * H_;
#pragma unroll
                for (int dt = 0; dt < 8; ++dt)
                    op[dt * 16 + col] =
                        f2bf((O[pt][dt][r] * aB + Of[row * 128 + dt * 16 + col] * aA) * inv);
            }
    }
}

// ---------------------------------------------------------------------------
extern "C" void kernel_launch(void* const* d_in, const int* in_sizes, int n_in,
                              void* d_out, int out_size, void* d_ws, size_t ws_size,
                              hipStream_t stream) {
    const float* x    = (const float*)d_in[0];
    const float* Wq   = (const float*)d_in[1];
    const float* Wk   = (const float*)d_in[2];
    const float* Wv   = (const float*)d_in[3];
    const float* Wo   = (const float*)d_in[4];
    const float* qnw  = (const float*)d_in[5];
    const float* knw  = (const float*)d_in[6];
    const float* cosb = (const float*)d_in[7];
    const float* sinb = (const float*)d_in[8];
    // d_in[9] = attn_mask: exact causal tril(0/-1e9) -> implemented directly

    const int M = B_ * T_;  // 4096
    // ws layout (u16 offsets), 42 MB proven footprint:
    //   WqT/WkT/WvT [0,6291456) dead after QKV; ctx [0,8388608) aliases them
    //   q [8388608,16777216) (WoT aliases after attn); k; v
    // x_bf16 lives in d_out (16.8 MB < 33.5 MB out_size); dead once the QKV
    // GEMM finishes, long before the final GEMM writes d_out.
    unsigned short* ws  = (unsigned short*)d_ws;
    unsigned short* WqT = ws;
    unsigned short* WkT = WqT + (size_t)2048 * 2048;
    unsigned short* WvT = WkT + (size_t)512 * 2048;
    unsigned short* ctx = ws;
    unsigned short* q   = ws + (size_t)8388608;
    unsigned short* k   = ws + (size_t)16777216;
    unsigned short* v   = ws + (size_t)18874368;
    unsigned short* WoT = q;
    unsigned short* xbf = (unsigned short*)d_out;

    transpose_cvt<<<(2048 / 64) * (2048 / 64), 256, 0, stream>>>(Wq, WqT, 2048, 2048);
    transpose_cvt<<<(2048 / 64) * (512 / 64),  256, 0, stream>>>(Wk, WkT, 2048, 512);
    transpose_cvt<<<(2048 / 64) * (512 / 64),  256, 0, stream>>>(Wv, WvT, 2048, 512);
    cvt_bf16<<<(M * C_) / (256 * 8), 256, 0, stream>>>(x, xbf);

    gemm_bt<false><<<(M / 128) * (3072 / 128), 256, 0, stream>>>(
        xbf, WqT, (void*)q, k, v, M, 3072, C_, 1);

    // Q pre-scaled by log2(e)/sqrt(128) for the exp2-domain softmax
    norm_rope<<<M * NQ_, 64, 0, stream>>>(q, qnw, cosb, sinb, NQ_, 0.12751743f);
    norm_rope<<<M * NKV_, 64, 0, stream>>>(k, knw, cosb, sinb, NKV_, 1.0f);

    flash_attn<<<256, 512, 0, stream>>>(q, k, v, ctx);

    transpose_cvt<<<(2048 / 64) * (2048 / 64), 256, 0, stream>>>(Wo, WoT, 2048, 2048);
    gemm_bt<true><<<(M / 128) * (C_ / 128), 256, 0, stream>>>(
        ctx, WoT, d_out, nullptr, nullptr, M, C_, NQ_ * H_, 0);
}

// Round 9
// 370.205 us; speedup vs baseline: 1.4452x; 1.0029x over previous
//
#include <hip/hip_runtime.h>
#include <hip/hip_bf16.h>

// Problem: B=2, T=2048, C=2048, NQ=16, NKV=4, H=128, EPS=1e-6
// DTYPE GROUND TRUTH (established rounds 1-6): ALL inputs f32, output f32.
// Internals: bf16 (weights pre-converted; x pre-converted to bf16 in d_out).
#define B_   2
#define T_   2048
#define C_   2048
#define NQ_  16
#define NKV_ 4
#define H_   128

using bf16x8 = __attribute__((ext_vector_type(8))) short;
using f32x4  = __attribute__((ext_vector_type(4))) float;

__device__ __forceinline__ unsigned short f2bf(float f) {
    __hip_bfloat16 h = __float2bfloat16(f);  // RNE
    union { __hip_bfloat16 h; unsigned short s; } c;
    c.h = h;
    return c.s;
}
__device__ __forceinline__ float bf2f(unsigned short s) {
    return __uint_as_float(((unsigned)s) << 16);
}
__device__ __forceinline__ bf16x8 pack8(float4 f0, float4 f1) {
    bf16x8 r;
    r[0] = (short)f2bf(f0.x); r[1] = (short)f2bf(f0.y);
    r[2] = (short)f2bf(f0.z); r[3] = (short)f2bf(f0.w);
    r[4] = (short)f2bf(f1.x); r[5] = (short)f2bf(f1.y);
    r[6] = (short)f2bf(f1.z); r[7] = (short)f2bf(f1.w);
    return r;
}

#define MFMA16(a, b, c) __builtin_amdgcn_mfma_f32_16x16x32_bf16(a, b, c, 0, 0, 0)

// async global->LDS: 16B per lane, LDS dst = wave-uniform base + lane*16
__device__ __forceinline__ void gl_lds16(const void* g, void* l) {
    __builtin_amdgcn_global_load_lds(
        (const __attribute__((address_space(1))) void*)g,
        (__attribute__((address_space(3))) void*)l, 16, 0, 0);
}

// ---------------------------------------------------------------------------
// Elementwise f32 -> bf16 convert (x pre-pass; dst aliases d_out scratch).
// ---------------------------------------------------------------------------
__global__ void cvt_bf16(const float* __restrict__ src,
                         unsigned short* __restrict__ dst) {
    const int i = (blockIdx.x * 256 + threadIdx.x) * 8;
    const float4 a = *(const float4*)(src + i);
    const float4 b = *(const float4*)(src + i + 4);
    *(bf16x8*)(dst + i) = pack8(a, b);
}

// ---------------------------------------------------------------------------
// 64x64-tile transpose + f32->bf16 convert: dst[c][r] = bf16(src[r][c]).
// ---------------------------------------------------------------------------
__global__ void transpose_cvt(const float* __restrict__ src,
                              unsigned short* __restrict__ dst,
                              int R, int Cc) {
    const int tc = Cc >> 6;
    const int r0 = (blockIdx.x / tc) * 64;
    const int c0 = (blockIdx.x % tc) * 64;
    __shared__ unsigned short Tl[64 * 65];
    const int tid = threadIdx.x;
#pragma unroll
    for (int it = 0; it < 16; ++it) {
        const int idx = it * 256 + tid;
        const int r = idx >> 6, c = idx & 63;
        Tl[c * 65 + r] = f2bf(src[(size_t)(r0 + r) * Cc + c0 + c]);
    }
    __syncthreads();
#pragma unroll
    for (int it = 0; it < 16; ++it) {
        const int idx = it * 256 + tid;
        const int c = idx >> 6, r = idx & 63;
        dst[(size_t)(c0 + c) * R + r0 + r] = Tl[c * 65 + r];
    }
}

// ---------------------------------------------------------------------------
// 128x128-tile GEMM v3 (T3/T4 pipelined): C = A @ Bt^T, A/B bf16 K-major.
//   Round-8 post-mortem: __syncthreads() drains vmcnt(0) with ZERO in-block
//   overlap -> staging latency exposed every K-step (the documented m97-
//   ceiling mechanism). Fix per T3 "minimum 2-phase" + T4 counted vmcnt:
//     prologue: stage(b0,t0); stage(b1,t1); vmcnt(4); barrier
//     iter t:   stage(b[(t+2)%3], t+2)   // issue EARLY
//               ds_read b[t%3]; 16 MFMA  // loads hide under compute
//               vmcnt(4); sched_barrier; s_barrier   // t+1 landed; never 0
//   Triple-buffered LDS 3x16KB = 48KB. Race audit: b[t%3] is re-staged only
//   at iter t+1 (after the end-of-t barrier); ds_read results are consumed
//   by MFMAs (lgkmcnt-waited) before each wave reaches that barrier.
//   Staging/XOR-swizzle/epilogues identical to round-8 verified code.
// ---------------------------------------------------------------------------
template <bool OUT_F32>
__global__ __launch_bounds__(256, 2) void gemm_bt(
    const unsigned short* __restrict__ Ab,
    const unsigned short* __restrict__ Bt,
    void* __restrict__ Cqv,
    unsigned short* __restrict__ Ck,
    unsigned short* __restrict__ Cv,
    int M, int N, int K, int fused) {
    const int ntn = N >> 7;
    const int cpx = gridDim.x >> 3;                       // nwg % 8 == 0
    const int wg  = (blockIdx.x & 7) * cpx + (blockIdx.x >> 3);
    const int tm  = wg / ntn;
    const int tn  = wg % ntn;

    const int tid  = threadIdx.x;
    const int wv   = tid >> 6;
    const int lane = tid & 63;
    const int col  = lane & 15;
    const int quad = lane >> 4;
    const int wm   = (wv & 1) * 64;
    const int wn   = (wv >> 1) * 64;

    __shared__ unsigned short Al[3][128 * 32];
    __shared__ unsigned short Bl[3][128 * 32];

    f32x4 acc[4][4];
#pragma unroll
    for (int mt = 0; mt < 4; ++mt)
#pragma unroll
        for (int nt = 0; nt < 4; ++nt) acc[mt][nt] = (f32x4){0.f, 0.f, 0.f, 0.f};

    // staging addresses: wave wv covers rows [wv*32, wv*32+32) in 2 slabs of 16
    const int rsl = lane >> 2;                      // 0..15 row within slab
    const int gsw = ((lane & 3) ^ (rsl & 3)) << 3;  // XOR-swizzled granule (u16)
    const int row0 = wv * 32 + rsl;
    const int row1 = row0 + 16;
    const size_t aoff0 = (size_t)(tm * 128 + row0) * K + gsw;
    const size_t aoff1 = (size_t)(tm * 128 + row1) * K + gsw;
    const size_t boff0 = (size_t)(tn * 128 + row0) * K + gsw;
    const size_t boff1 = (size_t)(tn * 128 + row1) * K + gsw;
    const int ld0 = (wv * 32) * 32;        // wave-uniform LDS offsets (u16)
    const int ld1 = (wv * 32 + 16) * 32;

    auto stage = [&](int buf, int k0) {
        gl_lds16(Ab + aoff0 + k0, &Al[buf][ld0]);
        gl_lds16(Ab + aoff1 + k0, &Al[buf][ld1]);
        gl_lds16(Bt + boff0 + k0, &Bl[buf][ld0]);
        gl_lds16(Bt + boff1 + k0, &Bl[buf][ld1]);
    };

    const int swq = (quad ^ (col & 3)) << 3;   // read-side XOR (u16 offset)
    const int NT  = K >> 5;                    // K-tiles of 32

    stage(0, 0);
    stage(1, 32);
    asm volatile("s_waitcnt vmcnt(4)" ::: "memory");   // tile 0 landed
    __builtin_amdgcn_sched_barrier(0);
    __builtin_amdgcn_s_barrier();

    int cur = 0;
    for (int t = 0; t < NT; ++t) {
        if (t + 2 < NT) {
            int b2 = cur + 2; if (b2 >= 3) b2 -= 3;
            stage(b2, (t + 2) << 5);           // issue early; lands under MFMA
        }

        bf16x8 af[4], bfv[4];
#pragma unroll
        for (int q = 0; q < 4; ++q) {
            af[q]  = *(const bf16x8*)(&Al[cur][(wm + q * 16 + col) * 32 + swq]);
            bfv[q] = *(const bf16x8*)(&Bl[cur][(wn + q * 16 + col) * 32 + swq]);
        }
#pragma unroll
        for (int mt = 0; mt < 4; ++mt)
#pragma unroll
            for (int nt = 0; nt < 4; ++nt)
                acc[mt][nt] = MFMA16(af[mt], bfv[nt], acc[mt][nt]);

        // tile t+1 must be landed; tile t+2's 4 loads may stay in flight
        asm volatile("s_waitcnt vmcnt(4)" ::: "memory");
        __builtin_amdgcn_sched_barrier(0);
        __builtin_amdgcn_s_barrier();
        ++cur; if (cur >= 3) cur -= 3;
    }

    const int nb = tn * 128;
    if constexpr (OUT_F32) {
        float* Co = (float*)Cqv;
#pragma unroll
        for (int mt = 0; mt < 4; ++mt)
#pragma unroll
            for (int nt = 0; nt < 4; ++nt)
#pragma unroll
                for (int r = 0; r < 4; ++r) {
                    const int row = tm * 128 + wm + mt * 16 + quad * 4 + r;
                    const int cc  = nb + wn + nt * 16 + col;
                    Co[(size_t)row * N + cc] = acc[mt][nt][r];
                }
    } else {
        unsigned short* Cb;
        int ldc, nc0;
        if (!fused)         { Cb = (unsigned short*)Cqv; ldc = N;    nc0 = nb;        }
        else if (nb < 2048) { Cb = (unsigned short*)Cqv; ldc = 2048; nc0 = nb;        }
        else if (nb < 2560) { Cb = Ck;                   ldc = 512;  nc0 = nb - 2048; }
        else                { Cb = Cv;                   ldc = 512;  nc0 = nb - 2560; }
#pragma unroll
        for (int mt = 0; mt < 4; ++mt)
#pragma unroll
            for (int nt = 0; nt < 4; ++nt)
#pragma unroll
                for (int r = 0; r < 4; ++r) {
                    const int row = tm * 128 + wm + mt * 16 + quad * 4 + r;
                    const int cc  = nc0 + wn + nt * 16 + col;
                    Cb[(size_t)row * ldc + cc] = f2bf(acc[mt][nt][r]);
                }
    }
}

// ---------------------------------------------------------------------------
// Fused per-head RMSNorm + RoPE. oscale folds log2(e)/sqrt(H) into Q so the
// flash kernel's scores come out pre-scaled for the exp2-domain softmax.
// ---------------------------------------------------------------------------
__global__ void norm_rope(unsigned short* __restrict__ buf,
                          const float* __restrict__ w,
                          const float* __restrict__ cosb,
                          const float* __restrict__ sinb,
                          int nheads, float oscale) {
    const int idx = blockIdx.x;
    const int h   = idx % nheads;
    const int bt  = idx / nheads;
    const int t   = bt % T_;
    unsigned short* row = buf + ((size_t)bt * nheads + h) * H_;
    const int l = threadIdx.x;  // 0..63

    const float x0 = bf2f(row[l]);
    const float x1 = bf2f(row[l + 64]);
    float ss = x0 * x0 + x1 * x1;
#pragma unroll
    for (int off = 32; off; off >>= 1) ss += __shfl_xor(ss, off);
    const float r = rsqrtf(ss * (1.0f / 128.0f) + 1e-6f) * oscale;

    const float n0 = x0 * r * w[l];
    const float n1 = x1 * r * w[l + 64];
    const float c0 = cosb[t * H_ + l];
    const float c1 = cosb[t * H_ + l + 64];
    const float s0 = sinb[t * H_ + l];
    const float s1 = sinb[t * H_ + l + 64];

    row[l]      = f2bf(n0 * c0 - n1 * s0);
    row[l + 64] = f2bf(n1 * c1 + n0 * s1);
}

// ---------------------------------------------------------------------------
// MFMA flash attention v6 (VERIFIED 106.4us, round 8) — unchanged.
//   KV-split pair schedule + in-LDS merge; K direct-to-registers; V staged
//   via regs->LDS with packed-transpose layout; swapped QK^T; in-lane
//   softmax; defer-max. 2 barriers/iteration.
// LDS = 36864(V) + 36864(P) + 1024(alf) + 2048(ml) = 76800 B.
// ---------------------------------------------------------------------------
__global__ __launch_bounds__(512, 2) void flash_attn(
    const unsigned short* __restrict__ qbuf,
    const unsigned short* __restrict__ kbuf,
    const unsigned short* __restrict__ vbuf,
    unsigned short* __restrict__ ctx) {
    const int blk = blockIdx.x;            // 256 blocks
    const int p   = blk & 7;               // pair: tiles p and 15-p
    const int h   = (blk >> 3) & 15;
    const int b   = blk >> 7;
    const int kvh = h >> 2;
    const int qtB = 15 - p;

    const int tid  = threadIdx.x;
    const int wave = tid >> 6;             // 0..7
    const int g    = wave >> 2;            // 0 = group A, 1 = group B
    const int gw   = wave & 3;             // wave-in-group
    const int lane = tid & 63;
    const int col  = lane & 15;
    const int quad = lane >> 4;
    const int gtid = gw * 64 + lane;       // 0..255 within group

    int w0 = (g ? qtB : p) * 128 + gw * 32;   // active 32 q-rows
    const int ph1 = 2 * p + 2;                // group A's own-tile chunk count

    __shared__ __align__(16) unsigned char smem[76800];
    unsigned short* Vg   = (unsigned short*)smem + g * 9216;              // [128][72]
    unsigned short* Pw   = (unsigned short*)(smem + 36864) + wave * 2304; // [32][72]
    float*          alfw = (float*)(smem + 73728) + wave * 32;            // [32]
    unsigned*       Vw   = (unsigned*)Vg;

    // Q fragments for active rows, pre-scaled by log2(e)/sqrt(H)
    bf16x8 qf[2][4];
    auto loadQ = [&]() {
#pragma unroll
        for (int nt = 0; nt < 2; ++nt)
#pragma unroll
            for (int ks = 0; ks < 4; ++ks) {
                const size_t off =
                    ((size_t)(b * T_ + w0 + nt * 16 + col) * NQ_ + h) * H_ + ks * 32 + quad * 8;
                qf[nt][ks] = *(const bf16x8*)(qbuf + off);
            }
    };
    loadQ();

    f32x4 O[2][8];
#pragma unroll
    for (int pt = 0; pt < 2; ++pt)
#pragma unroll
        for (int dt = 0; dt < 8; ++dt) O[pt][dt] = (f32x4){0.f, 0.f, 0.f, 0.f};
    float m_run[2] = {-3.0e38f, -3.0e38f};
    float l_run[2] = {0.f, 0.f};

    // ---- K direct-to-register ----
    bf16x8 kf[4][4];  // [mt][ks]
    const unsigned short* kb = kbuf + ((size_t)(b * T_) * NKV_ + kvh) * H_;
    const int koff = col * (NKV_ * H_) + quad * 8;
    auto loadK = [&](int j0) {
#pragma unroll
        for (int mt = 0; mt < 4; ++mt) {
            const unsigned short* kr = kb + (size_t)((j0 + mt * 16) * (NKV_ * H_) + koff);
#pragma unroll
            for (int ks = 0; ks < 4; ++ks)
                kf[mt][ks] = *(const bf16x8*)(kr + ks * 32);
        }
    };

    // ---- V staging (reg-staged, T14) ----
    uint4 va[4];
    const size_t kvstride = (size_t)NKV_ * H_;
    auto issueV = [&](int j0) {
#pragma unroll
        for (int it = 0; it < 2; ++it) {
            const int idx = it * 256 + gtid;  // 0..511
            const int kp  = idx & 31;
            const int dc  = idx >> 5;
            const size_t g0 = ((size_t)(b * T_ + j0 + 2 * kp) * NKV_ + kvh) * H_ + dc * 8;
            va[2 * it]     = *(const uint4*)(vbuf + g0);
            va[2 * it + 1] = *(const uint4*)(vbuf + g0 + kvstride);
        }
    };
    auto writeV = [&]() {
#pragma unroll
        for (int it = 0; it < 2; ++it) {
            const int idx = it * 256 + gtid;
            const int kp  = idx & 31;
            const int dc  = idx >> 5;
            const uint4 v0 = va[2 * it];
            const uint4 v1 = va[2 * it + 1];
            const int wb = dc * 288 + kp;
            Vw[wb + 0 * 36] = (v0.x & 0xFFFFu) | (v1.x << 16);
            Vw[wb + 1 * 36] = (v0.x >> 16)     | (v1.x & 0xFFFF0000u);
            Vw[wb + 2 * 36] = (v0.y & 0xFFFFu) | (v1.y << 16);
            Vw[wb + 3 * 36] = (v0.y >> 16)     | (v1.y & 0xFFFF0000u);
            Vw[wb + 4 * 36] = (v0.z & 0xFFFFu) | (v1.z << 16);
            Vw[wb + 5 * 36] = (v0.z >> 16)     | (v1.z & 0xFFFF0000u);
            Vw[wb + 6 * 36] = (v0.w & 0xFFFFu) | (v1.w << 16);
            Vw[wb + 7 * 36] = (v0.w >> 16)     | (v1.w & 0xFFFF0000u);
        }
    };

    // tile-A epilogue (group A only, no barriers inside)
    auto storeOut = [&]() {
        if (quad == 0) {
            alfw[col]      = 1.0f / l_run[0];
            alfw[col + 16] = 1.0f / l_run[1];
        }
        const f32x4 i0 = *(const f32x4*)&alfw[quad * 4];
        const f32x4 i1 = *(const f32x4*)&alfw[quad * 4 + 16];
#pragma unroll
        for (int pt = 0; pt < 2; ++pt)
#pragma unroll
            for (int r = 0; r < 4; ++r) {
                const float inv = pt ? i1[r] : i0[r];
                const int ig = w0 + pt * 16 + quad * 4 + r;
                unsigned short* op = ctx + ((size_t)(b * T_ + ig) * NQ_ + h) * H_;
#pragma unroll
                for (int dt = 0; dt < 8; ++dt)
                    op[dt * 16 + col] = f2bf(O[pt][dt][r] * inv);
            }
    };

    // group chunk schedule: B: 0..16; A: 0..ph1-1 (own), then 17..(31-2p)
    auto chunk_of = [&](int i) { return g ? i : (i < ph1 ? i : i + 15 - 2 * p); };

    loadK(0);
    issueV(0);

    for (int i = 0; i < 17; ++i) {
        const int j0 = chunk_of(i) * 64;
        __syncthreads();  // prior chunk's V/P reads complete; prefetched V landed
        writeV();
        __syncthreads();  // staged V visible

        if (i + 1 < 17) issueV(chunk_of(i + 1) * 64);

        // group A: transition from own tile to B-tile partial
        if (g == 0 && i == ph1) {
            storeOut();  // tile p is complete -> ctx
#pragma unroll
            for (int pt = 0; pt < 2; ++pt)
#pragma unroll
                for (int dt = 0; dt < 8; ++dt) O[pt][dt] = (f32x4){0.f, 0.f, 0.f, 0.f};
            m_run[0] = m_run[1] = -3.0e38f;
            l_run[0] = l_run[1] = 0.f;
            w0 = qtB * 128 + gw * 32;
            loadQ();
        }

        const bool act = (j0 <= w0 + 31);  // this wave has unmasked keys here

        // ---- swapped QK^T: St[key-tile][q-tile], 32 MFMAs, operands in regs ----
        f32x4 St[4][2];
        if (act) {
#pragma unroll
            for (int mt = 0; mt < 4; ++mt)
#pragma unroll
                for (int nt = 0; nt < 2; ++nt) St[mt][nt] = (f32x4){0.f, 0.f, 0.f, 0.f};
#pragma unroll
            for (int ks = 0; ks < 4; ++ks)
#pragma unroll
                for (int mt = 0; mt < 4; ++mt) {
                    St[mt][0] = MFMA16(kf[mt][ks], qf[0][ks], St[mt][0]);
                    St[mt][1] = MFMA16(kf[mt][ks], qf[1][ks], St[mt][1]);
                }
        }

        // refill kf for next chunk (after last use; unconditional so masked
        // waves keep the prefetch chain alive)
        if (i + 1 < 17) loadK(chunk_of(i + 1) * 64);

        if (!act) continue;

        // ---- mask (acc row = key, col = query) ----
        const bool needmask = (j0 + 63 > w0);
        if (needmask) {
            const int ig0 = w0 + col;
#pragma unroll
            for (int mt = 0; mt < 4; ++mt)
#pragma unroll
                for (int r = 0; r < 4; ++r) {
                    const int key = j0 + mt * 16 + quad * 4 + r;
                    if (key > ig0)      St[mt][0][r] = -3.0e38f;
                    if (key > ig0 + 16) St[mt][1][r] = -3.0e38f;
                }
        }

        // ---- in-lane row max ----
        float rm[2];
#pragma unroll
        for (int nt = 0; nt < 2; ++nt) {
            float m0 = fmaxf(fmaxf(St[0][nt][0], St[0][nt][1]),
                             fmaxf(St[0][nt][2], St[0][nt][3]));
#pragma unroll
            for (int mt = 1; mt < 4; ++mt)
                m0 = fmaxf(m0, fmaxf(fmaxf(St[mt][nt][0], St[mt][nt][1]),
                                     fmaxf(St[mt][nt][2], St[mt][nt][3])));
            m0 = fmaxf(m0, __shfl_xor(m0, 16));
            m0 = fmaxf(m0, __shfl_xor(m0, 32));
            rm[nt] = m0;
        }

        // ---- defer-max (THR=8, exp2 domain) ----
        const int defer = __all((rm[0] <= m_run[0] + 8.0f) && (rm[1] <= m_run[1] + 8.0f));
        if (!defer) {
            const float mn0 = fmaxf(m_run[0], rm[0]);
            const float mn1 = fmaxf(m_run[1], rm[1]);
            const float al0 = exp2f(m_run[0] - mn0);
            const float al1 = exp2f(m_run[1] - mn1);
            m_run[0] = mn0; m_run[1] = mn1;
            l_run[0] *= al0; l_run[1] *= al1;
            if (quad == 0) { alfw[col] = al0; alfw[col + 16] = al1; }
        }

        // ---- P = exp2(S - m), in-lane sum, b64 packed writes ----
        float ls0 = 0.f, ls1 = 0.f;
#pragma unroll
        for (int mt = 0; mt < 4; ++mt) {
            const float p0 = exp2f(St[mt][0][0] - m_run[0]);
            const float p1 = exp2f(St[mt][0][1] - m_run[0]);
            const float p2 = exp2f(St[mt][0][2] - m_run[0]);
            const float p3 = exp2f(St[mt][0][3] - m_run[0]);
            ls0 += (p0 + p1) + (p2 + p3);
            *(uint2*)(Pw + col * 72 + mt * 16 + quad * 4) =
                make_uint2((unsigned)f2bf(p0) | ((unsigned)f2bf(p1) << 16),
                           (unsigned)f2bf(p2) | ((unsigned)f2bf(p3) << 16));
            const float q0 = exp2f(St[mt][1][0] - m_run[1]);
            const float q1 = exp2f(St[mt][1][1] - m_run[1]);
            const float q2 = exp2f(St[mt][1][2] - m_run[1]);
            const float q3 = exp2f(St[mt][1][3] - m_run[1]);
            ls1 += (q0 + q1) + (q2 + q3);
            *(uint2*)(Pw + (col + 16) * 72 + mt * 16 + quad * 4) =
                make_uint2((unsigned)f2bf(q0) | ((unsigned)f2bf(q1) << 16),
                           (unsigned)f2bf(q2) | ((unsigned)f2bf(q3) << 16));
        }
        ls0 += __shfl_xor(ls0, 16); ls0 += __shfl_xor(ls0, 32);
        ls1 += __shfl_xor(ls1, 16); ls1 += __shfl_xor(ls1, 32);
        l_run[0] += ls0; l_run[1] += ls1;

        // ---- O rescale (only when not deferred) ----
        if (!defer) {
            const f32x4 a0 = *(const f32x4*)&alfw[quad * 4];
            const f32x4 a1 = *(const f32x4*)&alfw[quad * 4 + 16];
#pragma unroll
            for (int dt = 0; dt < 8; ++dt)
#pragma unroll
                for (int r = 0; r < 4; ++r) { O[0][dt][r] *= a0[r]; O[1][dt][r] *= a1[r]; }
        }

        // ---- PV: O += P(32x64) @ V(64x128), 32 MFMAs ----
#pragma unroll
        for (int ks = 0; ks < 2; ++ks) {
            const bf16x8 pa0 = *(const bf16x8*)(Pw + col * 72 + ks * 32 + quad * 8);
            const bf16x8 pa1 = *(const bf16x8*)(Pw + (col + 16) * 72 + ks * 32 + quad * 8);
#pragma unroll
            for (int dt = 0; dt < 8; ++dt) {
                const bf16x8 vf = *(const bf16x8*)(Vg + (dt * 16 + col) * 72 + ks * 32 + quad * 8);
                O[0][dt] = MFMA16(pa0, vf, O[0][dt]);
                O[1][dt] = MFMA16(pa1, vf, O[1][dt]);
            }
        }
    }

    // ---- merge: combine B-tile partials (A: keys >= 1088, B: keys < 1088) ----
    __syncthreads();  // all compute/LDS reads done; V/P buffers reusable
    float* mlA = (float*)(smem + 74752);  // [4][32][2]
    float* mlB = (float*)(smem + 75776);  // [4][32][2]
    if (g == 0) {
        float* Of = (float*)smem + gw * 4096;  // [32][128] raw O
        float* ml = mlA + gw * 64;
        if (quad == 0) {
            ml[2 * col]            = m_run[0]; ml[2 * col + 1]        = l_run[0];
            ml[2 * (col + 16)]     = m_run[1]; ml[2 * (col + 16) + 1] = l_run[1];
        }
#pragma unroll
        for (int pt = 0; pt < 2; ++pt)
#pragma unroll
            for (int dt = 0; dt < 8; ++dt)
#pragma unroll
                for (int r = 0; r < 4; ++r)
                    Of[(pt * 16 + quad * 4 + r) * 128 + dt * 16 + col] = O[pt][dt][r];
    }
    __syncthreads();
    if (g == 1) {
        float* Of = (float*)smem + gw * 4096;
        float* mA = mlA + gw * 64;
        float* mB = mlB + gw * 64;
        if (quad == 0) {
            mB[2 * col]            = m_run[0]; mB[2 * col + 1]        = l_run[0];
            mB[2 * (col + 16)]     = m_run[1]; mB[2 * (col + 16) + 1] = l_run[1];
        }
#pragma unroll
        for (int pt = 0; pt < 2; ++pt)
#pragma unroll
            for (int r = 0; r < 4; ++r) {
                const int row = pt * 16 + quad * 4 + r;
                const float mBv = mB[2 * row], lBv = mB[2 * row + 1];
                const float mAv = mA[2 * row], lAv = mA[2 * row + 1];
                const float m  = fmaxf(mAv, mBv);
                const float aB = exp2f(mBv - m);
                const float aA = exp2f(mAv - m);
                const float inv = 1.0f / (lBv * aB + lAv * aA);
                const int ig = w0 + row;
                unsigned short* op = ctx + ((size_t)(b * T_ + ig) * NQ_ + h) * H_;
#pragma unroll
                for (int dt = 0; dt < 8; ++dt)
                    op[dt * 16 + col] =
                        f2bf((O[pt][dt][r] * aB + Of[row * 128 + dt * 16 + col] * aA) * inv);
            }
    }
}

// ---------------------------------------------------------------------------
extern "C" void kernel_launch(void* const* d_in, const int* in_sizes, int n_in,
                              void* d_out, int out_size, void* d_ws, size_t ws_size,
                              hipStream_t stream) {
    const float* x    = (const float*)d_in[0];
    const float* Wq   = (const float*)d_in[1];
    const float* Wk   = (const float*)d_in[2];
    const float* Wv   = (const float*)d_in[3];
    const float* Wo   = (const float*)d_in[4];
    const float* qnw  = (const float*)d_in[5];
    const float* knw  = (const float*)d_in[6];
    const float* cosb = (const float*)d_in[7];
    const float* sinb = (const float*)d_in[8];
    // d_in[9] = attn_mask: exact causal tril(0/-1e9) -> implemented directly

    const int M = B_ * T_;  // 4096
    // ws layout (u16 offsets), 42 MB proven footprint:
    //   WqT/WkT/WvT [0,6291456) dead after QKV; ctx [0,8388608) aliases them
    //   q [8388608,16777216) (WoT aliases after attn); k; v
    // x_bf16 lives in d_out (16.8 MB < 33.5 MB out_size); dead once the QKV
    // GEMM finishes, long before the final GEMM writes d_out.
    unsigned short* ws  = (unsigned short*)d_ws;
    unsigned short* WqT = ws;
    unsigned short* WkT = WqT + (size_t)2048 * 2048;
    unsigned short* WvT = WkT + (size_t)512 * 2048;
    unsigned short* ctx = ws;
    unsigned short* q   = ws + (size_t)8388608;
    unsigned short* k   = ws + (size_t)16777216;
    unsigned short* v   = ws + (size_t)18874368;
    unsigned short* WoT = q;
    unsigned short* xbf = (unsigned short*)d_out;

    transpose_cvt<<<(2048 / 64) * (2048 / 64), 256, 0, stream>>>(Wq, WqT, 2048, 2048);
    transpose_cvt<<<(2048 / 64) * (512 / 64),  256, 0, stream>>>(Wk, WkT, 2048, 512);
    transpose_cvt<<<(2048 / 64) * (512 / 64),  256, 0, stream>>>(Wv, WvT, 2048, 512);
    cvt_bf16<<<(M * C_) / (256 * 8), 256, 0, stream>>>(x, xbf);

    gemm_bt<false><<<(M / 128) * (3072 / 128), 256, 0, stream>>>(
        xbf, WqT, (void*)q, k, v, M, 3072, C_, 1);

    // Q pre-scaled by log2(e)/sqrt(128) for the exp2-domain softmax
    norm_rope<<<M * NQ_, 64, 0, stream>>>(q, qnw, cosb, sinb, NQ_, 0.12751743f);
    norm_rope<<<M * NKV_, 64, 0, stream>>>(k, knw, cosb, sinb, NKV_, 1.0f);

    flash_attn<<<256, 512, 0, stream>>>(q, k, v, ctx);

    transpose_cvt<<<(2048 / 64) * (2048 / 64), 256, 0, stream>>>(Wo, WoT, 2048, 2048);
    gemm_bt<true><<<(M / 128) * (C_ / 128), 256, 0, stream>>>(
        ctx, WoT, d_out, nullptr, nullptr, M, C_, NQ_ * H_, 0);
}

// Round 10
// 353.887 us; speedup vs baseline: 1.5118x; 1.0461x over previous
//
#include <hip/hip_runtime.h>
#include <hip/hip_bf16.h>

// Problem: B=2, T=2048, C=2048, NQ=16, NKV=4, H=128, EPS=1e-6
// DTYPE GROUND TRUTH (established rounds 1-6): ALL inputs f32, output f32.
// Internals: bf16 (weights pre-converted; x pre-converted to bf16 in d_out).
#define B_   2
#define T_   2048
#define C_   2048
#define NQ_  16
#define NKV_ 4
#define H_   128

using bf16x8 = __attribute__((ext_vector_type(8))) short;
using f32x4  = __attribute__((ext_vector_type(4))) float;

__device__ __forceinline__ unsigned short f2bf(float f) {
    __hip_bfloat16 h = __float2bfloat16(f);  // RNE
    union { __hip_bfloat16 h; unsigned short s; } c;
    c.h = h;
    return c.s;
}
__device__ __forceinline__ float bf2f(unsigned short s) {
    return __uint_as_float(((unsigned)s) << 16);
}
__device__ __forceinline__ bf16x8 pack8(float4 f0, float4 f1) {
    bf16x8 r;
    r[0] = (short)f2bf(f0.x); r[1] = (short)f2bf(f0.y);
    r[2] = (short)f2bf(f0.z); r[3] = (short)f2bf(f0.w);
    r[4] = (short)f2bf(f1.x); r[5] = (short)f2bf(f1.y);
    r[6] = (short)f2bf(f1.z); r[7] = (short)f2bf(f1.w);
    return r;
}

#define MFMA16(a, b, c) __builtin_amdgcn_mfma_f32_16x16x32_bf16(a, b, c, 0, 0, 0)

// async global->LDS: 16B per lane, LDS dst = wave-uniform base + lane*16
__device__ __forceinline__ void gl_lds16(const void* g, void* l) {
    __builtin_amdgcn_global_load_lds(
        (const __attribute__((address_space(1))) void*)g,
        (__attribute__((address_space(3))) void*)l, 16, 0, 0);
}

// ---------------------------------------------------------------------------
// Elementwise f32 -> bf16 convert (x pre-pass; dst aliases d_out scratch).
// ---------------------------------------------------------------------------
__global__ void cvt_bf16(const float* __restrict__ src,
                         unsigned short* __restrict__ dst) {
    const int i = (blockIdx.x * 256 + threadIdx.x) * 8;
    const float4 a = *(const float4*)(src + i);
    const float4 b = *(const float4*)(src + i + 4);
    *(bf16x8*)(dst + i) = pack8(a, b);
}

// ---------------------------------------------------------------------------
// 64x64-tile transpose + f32->bf16 convert: dst[c][r] = bf16(src[r][c]).
// ---------------------------------------------------------------------------
__global__ void transpose_cvt(const float* __restrict__ src,
                              unsigned short* __restrict__ dst,
                              int R, int Cc) {
    const int tc = Cc >> 6;
    const int r0 = (blockIdx.x / tc) * 64;
    const int c0 = (blockIdx.x % tc) * 64;
    __shared__ unsigned short Tl[64 * 65];
    const int tid = threadIdx.x;
#pragma unroll
    for (int it = 0; it < 16; ++it) {
        const int idx = it * 256 + tid;
        const int r = idx >> 6, c = idx & 63;
        Tl[c * 65 + r] = f2bf(src[(size_t)(r0 + r) * Cc + c0 + c]);
    }
    __syncthreads();
#pragma unroll
    for (int it = 0; it < 16; ++it) {
        const int idx = it * 256 + tid;
        const int c = idx >> 6, r = idx & 63;
        dst[(size_t)(c0 + c) * R + r0 + r] = Tl[c * 65 + r];
    }
}

// ---------------------------------------------------------------------------
// 128x128-tile GEMM v4: C = A @ Bt^T, A/B bf16 K-major, T3/T4 pipelined
// (round-9 verified), PLUS fused RMSNorm+RoPE epilogue for the q/k tiles
// of the fused-QKV GEMM:
//   The 128-wide N-tile is exactly one head, so each block holds all 128
//   dims of 128 token rows in acc. Epilogue (q/k tiles only):
//     1) per-row sum(x^2): 4x shfl_xor over the 16-lane col group, then
//        cross-wave-pair combine via ssb[2][128] f32 in LDS.
//     2) normalize acc in-register: *= rsqrt(ss/128+eps)*w[d] (*log2e/sqrtH
//        for q — pre-scales the flash kernel's exp2-domain softmax).
//     3) publish normalized bf16 to nrm[128][132] LDS (stride 132 spreads
//        banks); partner dim d^64 lives in the partner wave.
//     4) rope: out = n[d]*cos -/+ n[d^64]*sin; store.
//   All epilogue LDS aliases the dead 48KB staging buffers (single gsm).
//   This deletes both norm_rope launches and the 48MB q/k re-read.
// LDS 48KB -> 3 blocks/CU at (256,3).
// ---------------------------------------------------------------------------
template <bool OUT_F32>
__global__ __launch_bounds__(256, 3) void gemm_bt(
    const unsigned short* __restrict__ Ab,
    const unsigned short* __restrict__ Bt,
    void* __restrict__ Cqv,
    unsigned short* __restrict__ Ck,
    unsigned short* __restrict__ Cv,
    const float* __restrict__ qnw,
    const float* __restrict__ knw,
    const float* __restrict__ cosb,
    const float* __restrict__ sinb,
    int M, int N, int K, int fused) {
    const int ntn = N >> 7;
    const int cpx = gridDim.x >> 3;                       // nwg % 8 == 0
    const int wg  = (blockIdx.x & 7) * cpx + (blockIdx.x >> 3);
    const int tm  = wg / ntn;
    const int tn  = wg % ntn;

    const int tid  = threadIdx.x;
    const int wv   = tid >> 6;
    const int lane = tid & 63;
    const int col  = lane & 15;
    const int quad = lane >> 4;
    const int wm   = (wv & 1) * 64;
    const int wn   = (wv >> 1) * 64;

    // 48 KB shared: staging (A bufs at [buf*4096), B bufs at [12288+buf*4096))
    // in the K-loop; aliased by the fused epilogue as nrm[128][132] u16
    // (=16896 u16) + ssb f32[256] at u16 offset 17408.
    __shared__ unsigned short gsm[24576];

    f32x4 acc[4][4];
#pragma unroll
    for (int mt = 0; mt < 4; ++mt)
#pragma unroll
        for (int nt = 0; nt < 4; ++nt) acc[mt][nt] = (f32x4){0.f, 0.f, 0.f, 0.f};

    // staging addresses: wave wv covers rows [wv*32, wv*32+32) in 2 slabs of 16
    const int rsl = lane >> 2;                      // 0..15 row within slab
    const int gsw = ((lane & 3) ^ (rsl & 3)) << 3;  // XOR-swizzled granule (u16)
    const int row0 = wv * 32 + rsl;
    const int row1 = row0 + 16;
    const size_t aoff0 = (size_t)(tm * 128 + row0) * K + gsw;
    const size_t aoff1 = (size_t)(tm * 128 + row1) * K + gsw;
    const size_t boff0 = (size_t)(tn * 128 + row0) * K + gsw;
    const size_t boff1 = (size_t)(tn * 128 + row1) * K + gsw;
    const int ld0 = (wv * 32) * 32;        // wave-uniform LDS offsets (u16)
    const int ld1 = (wv * 32 + 16) * 32;

    auto stage = [&](int buf, int k0) {
        gl_lds16(Ab + aoff0 + k0, gsm + buf * 4096 + ld0);
        gl_lds16(Ab + aoff1 + k0, gsm + buf * 4096 + ld1);
        gl_lds16(Bt + boff0 + k0, gsm + 12288 + buf * 4096 + ld0);
        gl_lds16(Bt + boff1 + k0, gsm + 12288 + buf * 4096 + ld1);
    };

    const int swq = (quad ^ (col & 3)) << 3;   // read-side XOR (u16 offset)
    const int NT  = K >> 5;                    // K-tiles of 32

    stage(0, 0);
    stage(1, 32);
    asm volatile("s_waitcnt vmcnt(4)" ::: "memory");   // tile 0 landed
    __builtin_amdgcn_sched_barrier(0);
    __builtin_amdgcn_s_barrier();

    int cur = 0;
    for (int t = 0; t < NT; ++t) {
        if (t + 2 < NT) {
            int b2 = cur + 2; if (b2 >= 3) b2 -= 3;
            stage(b2, (t + 2) << 5);           // issue early; lands under MFMA
        }

        bf16x8 af[4], bfv[4];
#pragma unroll
        for (int q = 0; q < 4; ++q) {
            af[q]  = *(const bf16x8*)(gsm + cur * 4096 + (wm + q * 16 + col) * 32 + swq);
            bfv[q] = *(const bf16x8*)(gsm + 12288 + cur * 4096 + (wn + q * 16 + col) * 32 + swq);
        }
#pragma unroll
        for (int mt = 0; mt < 4; ++mt)
#pragma unroll
            for (int nt = 0; nt < 4; ++nt)
                acc[mt][nt] = MFMA16(af[mt], bfv[nt], acc[mt][nt]);

        // tile t+1 must be landed; tile t+2's 4 loads may stay in flight
        asm volatile("s_waitcnt vmcnt(4)" ::: "memory");
        __builtin_amdgcn_sched_barrier(0);
        __builtin_amdgcn_s_barrier();
        ++cur; if (cur >= 3) cur -= 3;
    }

    const int nb = tn * 128;
    if constexpr (OUT_F32) {
        float* Co = (float*)Cqv;
#pragma unroll
        for (int mt = 0; mt < 4; ++mt)
#pragma unroll
            for (int nt = 0; nt < 4; ++nt)
#pragma unroll
                for (int r = 0; r < 4; ++r) {
                    const int row = tm * 128 + wm + mt * 16 + quad * 4 + r;
                    const int cc  = nb + wn + nt * 16 + col;
                    Co[(size_t)row * N + cc] = acc[mt][nt][r];
                }
    } else {
        unsigned short* Cb;
        int ldc, nc0;
        if (!fused)         { Cb = (unsigned short*)Cqv; ldc = N;    nc0 = nb;        }
        else if (nb < 2048) { Cb = (unsigned short*)Cqv; ldc = 2048; nc0 = nb;        }
        else if (nb < 2560) { Cb = Ck;                   ldc = 512;  nc0 = nb - 2048; }
        else                { Cb = Cv;                   ldc = 512;  nc0 = nb - 2560; }

        if (fused && nb < 2560) {
            // ---- fused RMSNorm + RoPE epilogue (q and k tiles) ----
            const float osc = (nb < 2048) ? 0.12751743f : 1.0f;  // log2e/sqrt(128)
            const float* wn_ptr = (nb < 2048) ? qnw : knw;
            unsigned short* nrm = gsm;                 // [128][132] u16
            float* ssb = (float*)(gsm + 17408);        // [2][128] f32

            __syncthreads();  // staging LDS dead; safe to alias

            // 1) per-row sum of squares
            float ssp[4][4];
#pragma unroll
            for (int mt = 0; mt < 4; ++mt)
#pragma unroll
                for (int r = 0; r < 4; ++r) {
                    float s = acc[mt][0][r] * acc[mt][0][r] +
                              acc[mt][1][r] * acc[mt][1][r] +
                              acc[mt][2][r] * acc[mt][2][r] +
                              acc[mt][3][r] * acc[mt][3][r];
                    s += __shfl_xor(s, 1);
                    s += __shfl_xor(s, 2);
                    s += __shfl_xor(s, 4);
                    s += __shfl_xor(s, 8);
                    ssp[mt][r] = s;
                }
            if (col == 0) {
#pragma unroll
                for (int mt = 0; mt < 4; ++mt)
#pragma unroll
                    for (int r = 0; r < 4; ++r)
                        ssb[(wv >> 1) * 128 + wm + mt * 16 + quad * 4 + r] = ssp[mt][r];
            }
            __syncthreads();

            // 2) normalize in-register, publish bf16 to nrm
            float wld[4];
#pragma unroll
            for (int nt = 0; nt < 4; ++nt) wld[nt] = wn_ptr[wn + nt * 16 + col];
#pragma unroll
            for (int mt = 0; mt < 4; ++mt)
#pragma unroll
                for (int r = 0; r < 4; ++r) {
                    const int rl = wm + mt * 16 + quad * 4 + r;
                    const float ss = ssb[rl] + ssb[128 + rl];
                    const float rinv = rsqrtf(ss * (1.0f / 128.0f) + 1e-6f) * osc;
#pragma unroll
                    for (int nt = 0; nt < 4; ++nt) {
                        acc[mt][nt][r] *= rinv * wld[nt];
                        nrm[rl * 132 + wn + nt * 16 + col] = f2bf(acc[mt][nt][r]);
                    }
                }
            __syncthreads();

            // 3) RoPE (pair d <-> d^64 across the wave pair) + store
#pragma unroll
            for (int mt = 0; mt < 4; ++mt)
#pragma unroll
                for (int r = 0; r < 4; ++r) {
                    const int rl = wm + mt * 16 + quad * 4 + r;
                    const int grow = tm * 128 + rl;
                    const float* cb = cosb + (size_t)(grow & 2047) * 128;
                    const float* sb = sinb + (size_t)(grow & 2047) * 128;
#pragma unroll
                    for (int nt = 0; nt < 4; ++nt) {
                        const int d = wn + nt * 16 + col;
                        const float nd = acc[mt][nt][r];
                        const float np = bf2f(nrm[rl * 132 + (d ^ 64)]);
                        const float c = cb[d], s = sb[d];
                        const float o = (wn == 0) ? nd * c - np * s
                                                  : nd * c + np * s;
                        Cb[(size_t)grow * ldc + nc0 + d] = f2bf(o);
                    }
                }
        } else {
            // v tile (or generic bf16 out): plain store
#pragma unroll
            for (int mt = 0; mt < 4; ++mt)
#pragma unroll
                for (int nt = 0; nt < 4; ++nt)
#pragma unroll
                    for (int r = 0; r < 4; ++r) {
                        const int row = tm * 128 + wm + mt * 16 + quad * 4 + r;
                        const int cc  = nc0 + wn + nt * 16 + col;
                        Cb[(size_t)row * ldc + cc] = f2bf(acc[mt][nt][r]);
                    }
        }
    }
}

// ---------------------------------------------------------------------------
// MFMA flash attention v6 (VERIFIED 106.4us, rounds 8-9) — unchanged.
//   KV-split pair schedule + in-LDS merge; K direct-to-registers; V staged
//   via regs->LDS with packed-transpose layout; swapped QK^T; in-lane
//   softmax; defer-max. 2 barriers/iteration.
// LDS = 36864(V) + 36864(P) + 1024(alf) + 2048(ml) = 76800 B.
// ---------------------------------------------------------------------------
__global__ __launch_bounds__(512, 2) void flash_attn(
    const unsigned short* __restrict__ qbuf,
    const unsigned short* __restrict__ kbuf,
    const unsigned short* __restrict__ vbuf,
    unsigned short* __restrict__ ctx) {
    const int blk = blockIdx.x;            // 256 blocks
    const int p   = blk & 7;               // pair: tiles p and 15-p
    const int h   = (blk >> 3) & 15;
    const int b   = blk >> 7;
    const int kvh = h >> 2;
    const int qtB = 15 - p;

    const int tid  = threadIdx.x;
    const int wave = tid >> 6;             // 0..7
    const int g    = wave >> 2;            // 0 = group A, 1 = group B
    const int gw   = wave & 3;             // wave-in-group
    const int lane = tid & 63;
    const int col  = lane & 15;
    const int quad = lane >> 4;
    const int gtid = gw * 64 + lane;       // 0..255 within group

    int w0 = (g ? qtB : p) * 128 + gw * 32;   // active 32 q-rows
    const int ph1 = 2 * p + 2;                // group A's own-tile chunk count

    __shared__ __align__(16) unsigned char smem[76800];
    unsigned short* Vg   = (unsigned short*)smem + g * 9216;              // [128][72]
    unsigned short* Pw   = (unsigned short*)(smem + 36864) + wave * 2304; // [32][72]
    float*          alfw = (float*)(smem + 73728) + wave * 32;            // [32]
    unsigned*       Vw   = (unsigned*)Vg;

    // Q fragments for active rows, pre-scaled by log2(e)/sqrt(H)
    bf16x8 qf[2][4];
    auto loadQ = [&]() {
#pragma unroll
        for (int nt = 0; nt < 2; ++nt)
#pragma unroll
            for (int ks = 0; ks < 4; ++ks) {
                const size_t off =
                    ((size_t)(b * T_ + w0 + nt * 16 + col) * NQ_ + h) * H_ + ks * 32 + quad * 8;
                qf[nt][ks] = *(const bf16x8*)(qbuf + off);
            }
    };
    loadQ();

    f32x4 O[2][8];
#pragma unroll
    for (int pt = 0; pt < 2; ++pt)
#pragma unroll
        for (int dt = 0; dt < 8; ++dt) O[pt][dt] = (f32x4){0.f, 0.f, 0.f, 0.f};
    float m_run[2] = {-3.0e38f, -3.0e38f};
    float l_run[2] = {0.f, 0.f};

    // ---- K direct-to-register ----
    bf16x8 kf[4][4];  // [mt][ks]
    const unsigned short* kb = kbuf + ((size_t)(b * T_) * NKV_ + kvh) * H_;
    const int koff = col * (NKV_ * H_) + quad * 8;
    auto loadK = [&](int j0) {
#pragma unroll
        for (int mt = 0; mt < 4; ++mt) {
            const unsigned short* kr = kb + (size_t)((j0 + mt * 16) * (NKV_ * H_) + koff);
#pragma unroll
            for (int ks = 0; ks < 4; ++ks)
                kf[mt][ks] = *(const bf16x8*)(kr + ks * 32);
        }
    };

    // ---- V staging (reg-staged, T14) ----
    uint4 va[4];
    const size_t kvstride = (size_t)NKV_ * H_;
    auto issueV = [&](int j0) {
#pragma unroll
        for (int it = 0; it < 2; ++it) {
            const int idx = it * 256 + gtid;  // 0..511
            const int kp  = idx & 31;
            const int dc  = idx >> 5;
            const size_t g0 = ((size_t)(b * T_ + j0 + 2 * kp) * NKV_ + kvh) * H_ + dc * 8;
            va[2 * it]     = *(const uint4*)(vbuf + g0);
            va[2 * it + 1] = *(const uint4*)(vbuf + g0 + kvstride);
        }
    };
    auto writeV = [&]() {
#pragma unroll
        for (int it = 0; it < 2; ++it) {
            const int idx = it * 256 + gtid;
            const int kp  = idx & 31;
            const int dc  = idx >> 5;
            const uint4 v0 = va[2 * it];
            const uint4 v1 = va[2 * it + 1];
            const int wb = dc * 288 + kp;
            Vw[wb + 0 * 36] = (v0.x & 0xFFFFu) | (v1.x << 16);
            Vw[wb + 1 * 36] = (v0.x >> 16)     | (v1.x & 0xFFFF0000u);
            Vw[wb + 2 * 36] = (v0.y & 0xFFFFu) | (v1.y << 16);
            Vw[wb + 3 * 36] = (v0.y >> 16)     | (v1.y & 0xFFFF0000u);
            Vw[wb + 4 * 36] = (v0.z & 0xFFFFu) | (v1.z << 16);
            Vw[wb + 5 * 36] = (v0.z >> 16)     | (v1.z & 0xFFFF0000u);
            Vw[wb + 6 * 36] = (v0.w & 0xFFFFu) | (v1.w << 16);
            Vw[wb + 7 * 36] = (v0.w >> 16)     | (v1.w & 0xFFFF0000u);
        }
    };

    // tile-A epilogue (group A only, no barriers inside)
    auto storeOut = [&]() {
        if (quad == 0) {
            alfw[col]      = 1.0f / l_run[0];
            alfw[col + 16] = 1.0f / l_run[1];
        }
        const f32x4 i0 = *(const f32x4*)&alfw[quad * 4];
        const f32x4 i1 = *(const f32x4*)&alfw[quad * 4 + 16];
#pragma unroll
        for (int pt = 0; pt < 2; ++pt)
#pragma unroll
            for (int r = 0; r < 4; ++r) {
                const float inv = pt ? i1[r] : i0[r];
                const int ig = w0 + pt * 16 + quad * 4 + r;
                unsigned short* op = ctx + ((size_t)(b * T_ + ig) * NQ_ + h) * H_;
#pragma unroll
                for (int dt = 0; dt < 8; ++dt)
                    op[dt * 16 + col] = f2bf(O[pt][dt][r] * inv);
            }
    };

    // group chunk schedule: B: 0..16; A: 0..ph1-1 (own), then 17..(31-2p)
    auto chunk_of = [&](int i) { return g ? i : (i < ph1 ? i : i + 15 - 2 * p); };

    loadK(0);
    issueV(0);

    for (int i = 0; i < 17; ++i) {
        const int j0 = chunk_of(i) * 64;
        __syncthreads();  // prior chunk's V/P reads complete; prefetched V landed
        writeV();
        __syncthreads();  // staged V visible

        if (i + 1 < 17) issueV(chunk_of(i + 1) * 64);

        // group A: transition from own tile to B-tile partial
        if (g == 0 && i == ph1) {
            storeOut();  // tile p is complete -> ctx
#pragma unroll
            for (int pt = 0; pt < 2; ++pt)
#pragma unroll
                for (int dt = 0; dt < 8; ++dt) O[pt][dt] = (f32x4){0.f, 0.f, 0.f, 0.f};
            m_run[0] = m_run[1] = -3.0e38f;
            l_run[0] = l_run[1] = 0.f;
            w0 = qtB * 128 + gw * 32;
            loadQ();
        }

        const bool act = (j0 <= w0 + 31);  // this wave has unmasked keys here

        // ---- swapped QK^T: St[key-tile][q-tile], 32 MFMAs, operands in regs ----
        f32x4 St[4][2];
        if (act) {
#pragma unroll
            for (int mt = 0; mt < 4; ++mt)
#pragma unroll
                for (int nt = 0; nt < 2; ++nt) St[mt][nt] = (f32x4){0.f, 0.f, 0.f, 0.f};
#pragma unroll
            for (int ks = 0; ks < 4; ++ks)
#pragma unroll
                for (int mt = 0; mt < 4; ++mt) {
                    St[mt][0] = MFMA16(kf[mt][ks], qf[0][ks], St[mt][0]);
                    St[mt][1] = MFMA16(kf[mt][ks], qf[1][ks], St[mt][1]);
                }
        }

        // refill kf for next chunk (after last use; unconditional so masked
        // waves keep the prefetch chain alive)
        if (i + 1 < 17) loadK(chunk_of(i + 1) * 64);

        if (!act) continue;

        // ---- mask (acc row = key, col = query) ----
        const bool needmask = (j0 + 63 > w0);
        if (needmask) {
            const int ig0 = w0 + col;
#pragma unroll
            for (int mt = 0; mt < 4; ++mt)
#pragma unroll
                for (int r = 0; r < 4; ++r) {
                    const int key = j0 + mt * 16 + quad * 4 + r;
                    if (key > ig0)      St[mt][0][r] = -3.0e38f;
                    if (key > ig0 + 16) St[mt][1][r] = -3.0e38f;
                }
        }

        // ---- in-lane row max ----
        float rm[2];
#pragma unroll
        for (int nt = 0; nt < 2; ++nt) {
            float m0 = fmaxf(fmaxf(St[0][nt][0], St[0][nt][1]),
                             fmaxf(St[0][nt][2], St[0][nt][3]));
#pragma unroll
            for (int mt = 1; mt < 4; ++mt)
                m0 = fmaxf(m0, fmaxf(fmaxf(St[mt][nt][0], St[mt][nt][1]),
                                     fmaxf(St[mt][nt][2], St[mt][nt][3])));
            m0 = fmaxf(m0, __shfl_xor(m0, 16));
            m0 = fmaxf(m0, __shfl_xor(m0, 32));
            rm[nt] = m0;
        }

        // ---- defer-max (THR=8, exp2 domain) ----
        const int defer = __all((rm[0] <= m_run[0] + 8.0f) && (rm[1] <= m_run[1] + 8.0f));
        if (!defer) {
            const float mn0 = fmaxf(m_run[0], rm[0]);
            const float mn1 = fmaxf(m_run[1], rm[1]);
            const float al0 = exp2f(m_run[0] - mn0);
            const float al1 = exp2f(m_run[1] - mn1);
            m_run[0] = mn0; m_run[1] = mn1;
            l_run[0] *= al0; l_run[1] *= al1;
            if (quad == 0) { alfw[col] = al0; alfw[col + 16] = al1; }
        }

        // ---- P = exp2(S - m), in-lane sum, b64 packed writes ----
        float ls0 = 0.f, ls1 = 0.f;
#pragma unroll
        for (int mt = 0; mt < 4; ++mt) {
            const float p0 = exp2f(St[mt][0][0] - m_run[0]);
            const float p1 = exp2f(St[mt][0][1] - m_run[0]);
            const float p2 = exp2f(St[mt][0][2] - m_run[0]);
            const float p3 = exp2f(St[mt][0][3] - m_run[0]);
            ls0 += (p0 + p1) + (p2 + p3);
            *(uint2*)(Pw + col * 72 + mt * 16 + quad * 4) =
                make_uint2((unsigned)f2bf(p0) | ((unsigned)f2bf(p1) << 16),
                           (unsigned)f2bf(p2) | ((unsigned)f2bf(p3) << 16));
            const float q0 = exp2f(St[mt][1][0] - m_run[1]);
            const float q1 = exp2f(St[mt][1][1] - m_run[1]);
            const float q2 = exp2f(St[mt][1][2] - m_run[1]);
            const float q3 = exp2f(St[mt][1][3] - m_run[1]);
            ls1 += (q0 + q1) + (q2 + q3);
            *(uint2*)(Pw + (col + 16) * 72 + mt * 16 + quad * 4) =
                make_uint2((unsigned)f2bf(q0) | ((unsigned)f2bf(q1) << 16),
                           (unsigned)f2bf(q2) | ((unsigned)f2bf(q3) << 16));
        }
        ls0 += __shfl_xor(ls0, 16); ls0 += __shfl_xor(ls0, 32);
        ls1 += __shfl_xor(ls1, 16); ls1 += __shfl_xor(ls1, 32);
        l_run[0] += ls0; l_run[1] += ls1;

        // ---- O rescale (only when not deferred) ----
        if (!defer) {
            const f32x4 a0 = *(const f32x4*)&alfw[quad * 4];
            const f32x4 a1 = *(const f32x4*)&alfw[quad * 4 + 16];
#pragma unroll
            for (int dt = 0; dt < 8; ++dt)
#pragma unroll
                for (int r = 0; r < 4; ++r) { O[0][dt][r] *= a0[r]; O[1][dt][r] *= a1[r]; }
        }

        // ---- PV: O += P(32x64) @ V(64x128), 32 MFMAs ----
#pragma unroll
        for (int ks = 0; ks < 2; ++ks) {
            const bf16x8 pa0 = *(const bf16x8*)(Pw + col * 72 + ks * 32 + quad * 8);
            const bf16x8 pa1 = *(const bf16x8*)(Pw + (col + 16) * 72 + ks * 32 + quad * 8);
#pragma unroll
            for (int dt = 0; dt < 8; ++dt) {
                const bf16x8 vf = *(const bf16x8*)(Vg + (dt * 16 + col) * 72 + ks * 32 + quad * 8);
                O[0][dt] = MFMA16(pa0, vf, O[0][dt]);
                O[1][dt] = MFMA16(pa1, vf, O[1][dt]);
            }
        }
    }

    // ---- merge: combine B-tile partials (A: keys >= 1088, B: keys < 1088) ----
    __syncthreads();  // all compute/LDS reads done; V/P buffers reusable
    float* mlA = (float*)(smem + 74752);  // [4][32][2]
    float* mlB = (float*)(smem + 75776);  // [4][32][2]
    if (g == 0) {
        float* Of = (float*)smem + gw * 4096;  // [32][128] raw O
        float* ml = mlA + gw * 64;
        if (quad == 0) {
            ml[2 * col]            = m_run[0]; ml[2 * col + 1]        = l_run[0];
            ml[2 * (col + 16)]     = m_run[1]; ml[2 * (col + 16) + 1] = l_run[1];
        }
#pragma unroll
        for (int pt = 0; pt < 2; ++pt)
#pragma unroll
            for (int dt = 0; dt < 8; ++dt)
#pragma unroll
                for (int r = 0; r < 4; ++r)
                    Of[(pt * 16 + quad * 4 + r) * 128 + dt * 16 + col] = O[pt][dt][r];
    }
    __syncthreads();
    if (g == 1) {
        float* Of = (float*)smem + gw * 4096;
        float* mA = mlA + gw * 64;
        float* mB = mlB + gw * 64;
        if (quad == 0) {
            mB[2 * col]            = m_run[0]; mB[2 * col + 1]        = l_run[0];
            mB[2 * (col + 16)]     = m_run[1]; mB[2 * (col + 16) + 1] = l_run[1];
        }
#pragma unroll
        for (int pt = 0; pt < 2; ++pt)
#pragma unroll
            for (int r = 0; r < 4; ++r) {
                const int row = pt * 16 + quad * 4 + r;
                const float mBv = mB[2 * row], lBv = mB[2 * row + 1];
                const float mAv = mA[2 * row], lAv = mA[2 * row + 1];
                const float m  = fmaxf(mAv, mBv);
                const float aB = exp2f(mBv - m);
                const float aA = exp2f(mAv - m);
                const float inv = 1.0f / (lBv * aB + lAv * aA);
                const int ig = w0 + row;
                unsigned short* op = ctx + ((size_t)(b * T_ + ig) * NQ_ + h) * H_;
#pragma unroll
                for (int dt = 0; dt < 8; ++dt)
                    op[dt * 16 + col] =
                        f2bf((O[pt][dt][r] * aB + Of[row * 128 + dt * 16 + col] * aA) * inv);
            }
    }
}

// ---------------------------------------------------------------------------
extern "C" void kernel_launch(void* const* d_in, const int* in_sizes, int n_in,
                              void* d_out, int out_size, void* d_ws, size_t ws_size,
                              hipStream_t stream) {
    const float* x    = (const float*)d_in[0];
    const float* Wq   = (const float*)d_in[1];
    const float* Wk   = (const float*)d_in[2];
    const float* Wv   = (const float*)d_in[3];
    const float* Wo   = (const float*)d_in[4];
    const float* qnw  = (const float*)d_in[5];
    const float* knw  = (const float*)d_in[6];
    const float* cosb = (const float*)d_in[7];
    const float* sinb = (const float*)d_in[8];
    // d_in[9] = attn_mask: exact causal tril(0/-1e9) -> implemented directly

    const int M = B_ * T_;  // 4096
    // ws layout (u16 offsets), 42 MB proven footprint:
    //   WqT/WkT/WvT [0,6291456) dead after QKV; ctx [0,8388608) aliases them
    //   q [8388608,16777216) (WoT aliases after attn); k; v
    // x_bf16 lives in d_out (16.8 MB < 33.5 MB out_size); dead once the QKV
    // GEMM finishes, long before the final GEMM writes d_out.
    unsigned short* ws  = (unsigned short*)d_ws;
    unsigned short* WqT = ws;
    unsigned short* WkT = WqT + (size_t)2048 * 2048;
    unsigned short* WvT = WkT + (size_t)512 * 2048;
    unsigned short* ctx = ws;
    unsigned short* q   = ws + (size_t)8388608;
    unsigned short* k   = ws + (size_t)16777216;
    unsigned short* v   = ws + (size_t)18874368;
    unsigned short* WoT = q;
    unsigned short* xbf = (unsigned short*)d_out;

    transpose_cvt<<<(2048 / 64) * (2048 / 64), 256, 0, stream>>>(Wq, WqT, 2048, 2048);
    transpose_cvt<<<(2048 / 64) * (512 / 64),  256, 0, stream>>>(Wk, WkT, 2048, 512);
    transpose_cvt<<<(2048 / 64) * (512 / 64),  256, 0, stream>>>(Wv, WvT, 2048, 512);
    cvt_bf16<<<(M * C_) / (256 * 8), 256, 0, stream>>>(x, xbf);

    // QKV GEMM with fused RMSNorm+RoPE epilogue (q pre-scaled by log2e/sqrtH)
    gemm_bt<false><<<(M / 128) * (3072 / 128), 256, 0, stream>>>(
        xbf, WqT, (void*)q, k, v, qnw, knw, cosb, sinb, M, 3072, C_, 1);

    flash_attn<<<256, 512, 0, stream>>>(q, k, v, ctx);

    transpose_cvt<<<(2048 / 64) * (2048 / 64), 256, 0, stream>>>(Wo, WoT, 2048, 2048);
    gemm_bt<true><<<(M / 128) * (C_ / 128), 256, 0, stream>>>(
        ctx, WoT, d_out, nullptr, nullptr, nullptr, nullptr, nullptr, nullptr,
        M, C_, NQ_ * H_, 0);
}